// Round 6
// baseline (298.678 us; speedup 1.0000x reference)
//
#include <hip/hip_runtime.h>
#include <cstdint>

// GNN: 2-layer GraphSAGE (mean aggr, L2-normalize) + BatchNorm(train) + ReLU.
// N=100000 nodes, E=800000 edges, C: 128 -> 128 -> 47.
//
// Round 16: k_gemm1 still top actionable dispatch (40.4us; MfmaUtil 5.5%,
// HBM 16%, occupancy 15% -- latency-bound on the per-kt vmcnt(0) drain + 2
// barriers). Observation: LDS tile reuse factor is only 2 (each staged row
// read by exactly 2 waves) -> staging buys nothing. Rewrite both GEMMs as
// DIRECT-FROM-GLOBAL MFMA: each wave loads its A/B fragments straight into
// VGPRs (global_load_dwordx4; L1/L2 absorb the 2x duplication), K-loop has
// ZERO barriers / ZERO LDS tiles, compiler fully unrolls and pipelines 64
// independent loads against MFMAs with automatic counted vmcnt. Epilogues
// keep their __syncthreads discipline on small dedicated LDS arrays.
// gemm2: BN+ReLU applied to A-fragment after load (identical arithmetic).
// Rest unchanged from R15 (passed, 270.1us).

typedef __attribute__((ext_vector_type(8))) short s8v;
typedef __attribute__((ext_vector_type(4))) short s4v;
typedef __attribute__((ext_vector_type(4))) float fx4;

#define CSR_CHUNK 8192
#define CSR_SH 8            // 256 nodes per bucket
#define CSR_NBPAD 512       // padded bucket count (NB = ceil(n/256) = 391)
#define CSR_BUFCAP 3072     // LDS srcbuf cap per bucket (mean 2046, +20 sigma)

static __device__ __forceinline__ float bf2f(unsigned short h) {
    union { unsigned int u; float f; } c; c.u = (unsigned int)h << 16; return c.f;
}
static __device__ __forceinline__ unsigned short f2bf(float f) {
    union { float f; unsigned int u; } c; c.f = f;
    unsigned int u = c.u;
    return (unsigned short)((u + 0x7FFF + ((u >> 16) & 1)) >> 16);   // RNE
}

// ---- merged prep: x->bf16 | weight casts | stats zero | bcount histograms.
__global__ __launch_bounds__(256) void k_prep(
        const float* __restrict__ x, const float* __restrict__ w1l,
        const float* __restrict__ w1r, const float* __restrict__ w2l,
        const float* __restrict__ w2r, const int* __restrict__ ei,
        unsigned short* __restrict__ xb, unsigned short* __restrict__ wB1,
        unsigned short* __restrict__ wB2p, float* __restrict__ stats,
        int* __restrict__ counts, int n, int nE, int prepBlocks) {
    __shared__ int hist[CSR_NBPAD];
    int t = threadIdx.x;
    if ((int)blockIdx.x >= prepBlocks) {
        int chunk = blockIdx.x - prepBlocks;
        hist[t] = 0; hist[t + 256] = 0;
        __syncthreads();
        int e0 = chunk * CSR_CHUNK;
        int e1 = min(e0 + CSR_CHUNK, nE);
        for (int e = e0 + t; e < e1; e += 256)
            atomicAdd(&hist[ei[nE + e] >> CSR_SH], 1);
        __syncthreads();
        counts[chunk * CSR_NBPAD + t] = hist[t];
        counts[chunk * CSR_NBPAD + t + 256] = hist[t + 256];
        return;
    }
    int idx = blockIdx.x * 256 + t;
    int nx = n * 16;
    if (idx < nx) {
        float4 a = ((const float4*)x)[idx * 2];
        float4 b = ((const float4*)x)[idx * 2 + 1];
        union { s8v v; unsigned short u[8]; } o;
        o.u[0] = f2bf(a.x); o.u[1] = f2bf(a.y); o.u[2] = f2bf(a.z); o.u[3] = f2bf(a.w);
        o.u[4] = f2bf(b.x); o.u[5] = f2bf(b.y); o.u[6] = f2bf(b.z); o.u[7] = f2bf(b.w);
        ((s8v*)xb)[idx] = o.v;
        return;
    }
    idx -= nx;
    if (idx < 32768) {
        int j = idx >> 8, k = idx & 255;
        float v = (k < 128) ? w1l[j * 128 + k] : w1r[j * 128 + (k - 128)];
        wB1[idx] = f2bf(v);
        return;
    }
    idx -= 32768;
    if (idx < 16384) {
        int j = idx >> 7, k = idx & 127;
        float v = 0.f;
        if (j < 47)      v = w2l[j * 128 + k];
        else if (j < 94) v = w2r[(j - 47) * 128 + k];
        wB2p[idx] = f2bf(v);
        return;
    }
    idx -= 16384;
    if (idx < 256) stats[idx] = 0.f;
}

// ---- CSR build: bucketed counting sort -------------------------------
__global__ __launch_bounds__(256) void k_bmeta(
        const int* __restrict__ counts, int* __restrict__ bucketStart,
        int* __restrict__ gcur, int nCh, int NB) {
    __shared__ int tot[CSR_NBPAD], tot2[CSR_NBPAD], sh[256], bs[CSR_NBPAD];
    int t = threadIdx.x;
    int tl = t & 127, g = t >> 7;
    int half = (nCh + 1) >> 1;
    int c0 = g * half, c1 = min(nCh, c0 + half);
    int4 s4 = {0, 0, 0, 0};
    for (int c = c0; c < c1; ++c) {
        int4 v = *(const int4*)(counts + (size_t)c * CSR_NBPAD + tl * 4);
        s4.x += v.x; s4.y += v.y; s4.z += v.z; s4.w += v.w;
    }
    *(int4*)((g ? tot2 : tot) + tl * 4) = s4;
    __syncthreads();
    tot[t] += tot2[t];
    tot[t + 256] += tot2[t + 256];
    __syncthreads();
    int pairSum = tot[2 * t] + tot[2 * t + 1];
    sh[t] = pairSum;
    __syncthreads();
    for (int off = 1; off < 256; off <<= 1) {
        int add = (t >= off) ? sh[t - off] : 0;
        __syncthreads();
        sh[t] += add;
        __syncthreads();
    }
    int excl = sh[t] - pairSum;
    bs[2 * t] = excl;
    bs[2 * t + 1] = excl + tot[2 * t];
    __syncthreads();
    for (int b = t; b <= NB; b += 256) bucketStart[b] = bs[b];
    for (int b = t; b < CSR_NBPAD; b += 256) gcur[b] = bs[b];
}

__global__ __launch_bounds__(256) void k_bfill(
        const int* __restrict__ ei, const int* __restrict__ counts,
        int* __restrict__ gcur, int* __restrict__ pairs, int nE) {
    __shared__ int cur[CSR_NBPAD];
    int t = threadIdx.x;
    #pragma unroll
    for (int i = 0; i < 2; ++i) {
        int b = t + i * 256;
        int h = counts[blockIdx.x * CSR_NBPAD + b];
        cur[b] = h ? atomicAdd(&gcur[b], h) : 0;
    }
    __syncthreads();
    int e0 = blockIdx.x * CSR_CHUNK;
    int e1 = min(e0 + CSR_CHUNK, nE);
    for (int e = e0 + t; e < e1; e += 256) {
        int s = ei[e];
        int d = ei[nE + e];
        int p = atomicAdd(&cur[d >> CSR_SH], 1);
        pairs[p] = (s << 8) | (d & 255);
    }
}

__global__ __launch_bounds__(256) void k_csr(
        const int* __restrict__ pairs, const int* __restrict__ bucketStart,
        int* __restrict__ deg, int* __restrict__ rowStart,
        int* __restrict__ srcIdx, int n) {
    __shared__ int cnt[256], scn[256], cur[256];
    __shared__ int buf[CSR_BUFCAP];
    int t = threadIdx.x;
    int bkt = blockIdx.x;
    int eBeg = bucketStart[bkt], eEnd = bucketStart[bkt + 1];
    int node0 = bkt << CSR_SH;
    cnt[t] = 0;
    __syncthreads();
    for (int e = eBeg + t; e < eEnd; e += 256)
        atomicAdd(&cnt[pairs[e] & 255], 1);
    __syncthreads();
    int myc = cnt[t];
    scn[t] = myc;
    __syncthreads();
    for (int off = 1; off < 256; off <<= 1) {
        int add = (t >= off) ? scn[t - off] : 0;
        __syncthreads();
        scn[t] += add;
        __syncthreads();
    }
    int excl = scn[t] - myc;
    cur[t] = excl;
    int node = node0 + t;
    if (node < n) { deg[node] = myc; rowStart[node] = eBeg + excl; }
    __syncthreads();
    for (int e = eBeg + t; e < eEnd; e += 256) {
        int pk = pairs[e];
        int p = atomicAdd(&cur[pk & 255], 1);
        int src = pk >> 8;
        if (p < CSR_BUFCAP) buf[p] = src;
        else srcIdx[eBeg + p] = src;   // statistically never at this size
    }
    __syncthreads();
    int m = min(eEnd - eBeg, CSR_BUFCAP);
    for (int i = t; i < m; i += 256) srcIdx[eBeg + i] = buf[i];
}

// ---- layer-1 gather (bf16): 16 lanes/node, lane owns 8 ch; 4-edge unroll.
__global__ __launch_bounds__(256) void k_gather1(
        const unsigned short* __restrict__ xb, const int* __restrict__ rowStart,
        const int* __restrict__ deg, const int* __restrict__ srcIdx,
        unsigned short* __restrict__ aggb, int n) {
    int t = threadIdx.x;
    int q = t & 15, grp = t >> 4;
    int node = blockIdx.x * 16 + grp;
    if (node >= n) return;
    int beg = rowStart[node];
    int d = deg[node];
    int end = beg + d;
    float a0[8] = {}, a1[8] = {}, a2[8] = {}, a3[8] = {};
    int e = beg;
    for (; e + 4 <= end; e += 4) {
        int s0 = srcIdx[e], s1v = srcIdx[e + 1], s2 = srcIdx[e + 2], s3 = srcIdx[e + 3];
        s8v v0 = *(const s8v*)(xb + (size_t)s0 * 128 + q * 8);
        s8v v1 = *(const s8v*)(xb + (size_t)s1v * 128 + q * 8);
        s8v v2 = *(const s8v*)(xb + (size_t)s2 * 128 + q * 8);
        s8v v3 = *(const s8v*)(xb + (size_t)s3 * 128 + q * 8);
        #pragma unroll
        for (int u = 0; u < 8; ++u) {
            a0[u] += bf2f((unsigned short)v0[u]);
            a1[u] += bf2f((unsigned short)v1[u]);
            a2[u] += bf2f((unsigned short)v2[u]);
            a3[u] += bf2f((unsigned short)v3[u]);
        }
    }
    for (; e < end; ++e) {
        s8v v0 = *(const s8v*)(xb + (size_t)srcIdx[e] * 128 + q * 8);
        #pragma unroll
        for (int u = 0; u < 8; ++u) a0[u] += bf2f((unsigned short)v0[u]);
    }
    float ic = 1.0f / fmaxf((float)d, 1.0f);
    union { s8v v; unsigned short u[8]; } o;
    #pragma unroll
    for (int u = 0; u < 8; ++u)
        o.u[u] = f2bf((a0[u] + a1[u] + a2[u] + a3[u]) * ic);
    *(s8v*)(aggb + (size_t)node * 128 + q * 8) = o.v;
}

// ---- GEMM1 (bf16 MFMA): block 128x128, K=256 (aggb then xb).
// Direct-from-global fragments: no LDS tiles, no K-loop barriers. Each wave
// loads its A rows (16 rows x 16B, L1-coalesced) and B rows straight into
// VGPRs; compiler pipelines loads vs MFMA with counted vmcnt.
__global__ __launch_bounds__(256, 3) void k_gemm1(
        const unsigned short* __restrict__ xb, const unsigned short* __restrict__ aggb,
        const unsigned short* __restrict__ wB1, const float* __restrict__ b1l,
        unsigned short* __restrict__ s1b, float* __restrict__ stats, int n) {
    __shared__ float norm2[256];   // [128][2]
    __shared__ float invn[128];
    __shared__ float statS[256];   // [128][2]
    __shared__ float statQ[256];   // [128][2]
    int t = threadIdx.x;
    int w = t >> 6, L = t & 63;
    int q = L >> 4, lm = L & 15;
    int wr0 = (w >> 1) * 64;     // wave row base
    int wc0 = (w & 1) * 64;      // wave col base
    int r0 = blockIdx.x * 128;

    int arow[4], brow[4];
    #pragma unroll
    for (int r = 0; r < 4; ++r) {
        int gr = r0 + wr0 + r * 16 + lm;
        arow[r] = gr < n ? gr : (n - 1);   // clamp: garbage rows feed unstored outputs
        brow[r] = wc0 + r * 16 + lm;
    }

    fx4 acc[4][4];
    fx4 z4 = {0.f, 0.f, 0.f, 0.f};
    #pragma unroll
    for (int r = 0; r < 4; ++r)
        #pragma unroll
        for (int c = 0; c < 4; ++c) acc[r][c] = z4;

    #pragma unroll
    for (int kt = 0; kt < 8; ++kt) {
        const unsigned short* src = (kt < 4) ? aggb : xb;
        int kb = (kt & 3) * 32 + q * 8;
        s8v af[4], bfr[4];
        #pragma unroll
        for (int r = 0; r < 4; ++r)
            af[r] = *(const s8v*)(src + (size_t)arow[r] * 128 + kb);
        #pragma unroll
        for (int c = 0; c < 4; ++c)
            bfr[c] = *(const s8v*)(wB1 + (size_t)brow[c] * 256 + kt * 32 + q * 8);
        #pragma unroll
        for (int r = 0; r < 4; ++r)
            #pragma unroll
            for (int c = 0; c < 4; ++c)
                acc[r][c] = __builtin_amdgcn_mfma_f32_16x16x32_bf16(af[r], bfr[c], acc[r][c], 0, 0, 0);
    }

    // ---- epilogue: bias -> row L2-norm -> scale -> bf16 store -> BN stats
    float bj[4];
    #pragma unroll
    for (int c = 0; c < 4; ++c) bj[c] = b1l[wc0 + c * 16 + lm];
    #pragma unroll
    for (int r = 0; r < 4; ++r)
        #pragma unroll
        for (int c = 0; c < 4; ++c) acc[r][c] += bj[c];

    fx4 pr[4];
    #pragma unroll
    for (int r = 0; r < 4; ++r) {
        fx4 p = acc[r][0] * acc[r][0];
        #pragma unroll
        for (int c = 1; c < 4; ++c) p += acc[r][c] * acc[r][c];
        #pragma unroll
        for (int off = 1; off <= 8; off <<= 1)
            #pragma unroll
            for (int i2 = 0; i2 < 4; ++i2) p[i2] += __shfl_xor(p[i2], off, 64);
        pr[r] = p;
    }

    if (lm == 0) {
        #pragma unroll
        for (int r = 0; r < 4; ++r)
            #pragma unroll
            for (int i = 0; i < 4; ++i)
                norm2[(wr0 + r * 16 + q * 4 + i) * 2 + (w & 1)] = pr[r][i];
    }
    __syncthreads();
    if (t < 128) {
        float s = norm2[t * 2] + norm2[t * 2 + 1];
        invn[t] = 1.0f / fmaxf(sqrtf(s), 1e-12f);
    }
    __syncthreads();

    float cS[4] = {}, cQ[4] = {};
    #pragma unroll
    for (int r = 0; r < 4; ++r) {
        int rowb = wr0 + r * 16 + q * 4;
        fx4 iv = *(const fx4*)&invn[rowb];
        #pragma unroll
        for (int c = 0; c < 4; ++c) {
            fx4 v = acc[r][c] * iv;
            int col = wc0 + c * 16 + lm;
            #pragma unroll
            for (int i = 0; i < 4; ++i) {
                int gr = r0 + rowb + i;
                if (gr < n) {
                    s1b[(size_t)gr * 128 + col] = f2bf(v[i]);
                    cS[c] += v[i];
                    cQ[c] += v[i] * v[i];
                }
            }
        }
    }
    #pragma unroll
    for (int off = 16; off <= 32; off <<= 1)
        #pragma unroll
        for (int c = 0; c < 4; ++c) {
            cS[c] += __shfl_xor(cS[c], off, 64);
            cQ[c] += __shfl_xor(cQ[c], off, 64);
        }
    if (q == 0) {
        #pragma unroll
        for (int c = 0; c < 4; ++c) {
            int col = wc0 + c * 16 + lm;
            statS[col * 2 + (w >> 1)] = cS[c];
            statQ[col * 2 + (w >> 1)] = cQ[c];
        }
    }
    __syncthreads();
    if (t < 128) {
        atomicAdd(&stats[t],       statS[t * 2] + statS[t * 2 + 1]);
        atomicAdd(&stats[128 + t], statQ[t * 2] + statQ[t * 2 + 1]);
    }
}

// ---- GEMM2 (bf16 MFMA) with inline BN finalize. Direct-from-global
// fragments; BN+ReLU applied to the A-fragment after load (identical
// arithmetic -> identical bf16). y2b stride 64, rbuf stride 48.
__global__ __launch_bounds__(256, 3) void k_gemm2(
        const unsigned short* __restrict__ s1b, const unsigned short* __restrict__ wB2p,
        const float* __restrict__ stats, const float* __restrict__ gamma,
        const float* __restrict__ beta, const float* __restrict__ b2l,
        unsigned short* __restrict__ y2b, float* __restrict__ rbuf, int n) {
    __shared__ __align__(16) float abuf[128];
    __shared__ __align__(16) float bbuf[128];
    int t = threadIdx.x;
    int w = t >> 6, L = t & 63;
    int q = L >> 4, lm = L & 15;
    int wr0 = (w >> 1) * 64, wc0 = (w & 1) * 64;
    int r0 = blockIdx.x * 128;

    if (t < 128) {
        float s = stats[t], qv = stats[128 + t];
        float fn = (float)n;
        float mean = s / fn;
        float var = qv / fn - mean * mean;   // biased variance
        float istd = rsqrtf(var + 1e-5f);
        float a = gamma[t] * istd;
        abuf[t] = a;
        bbuf[t] = beta[t] - mean * a;
    }
    __syncthreads();   // abuf/bbuf visible to all

    int arow[4], brow[4];
    #pragma unroll
    for (int r = 0; r < 4; ++r) {
        int gr = r0 + wr0 + r * 16 + lm;
        arow[r] = gr < n ? gr : (n - 1);
        brow[r] = wc0 + r * 16 + lm;
    }

    fx4 acc[4][4];
    fx4 z4 = {0.f, 0.f, 0.f, 0.f};
    #pragma unroll
    for (int r = 0; r < 4; ++r)
        #pragma unroll
        for (int c = 0; c < 4; ++c) acc[r][c] = z4;

    #pragma unroll
    for (int kt = 0; kt < 4; ++kt) {
        int kb = kt * 32 + q * 8;
        fx4 a0 = *(const fx4*)&abuf[kb];
        fx4 a1 = *(const fx4*)&abuf[kb + 4];
        fx4 b0 = *(const fx4*)&bbuf[kb];
        fx4 b1 = *(const fx4*)&bbuf[kb + 4];
        s8v af[4], bfr[4];
        #pragma unroll
        for (int r = 0; r < 4; ++r) {
            s8v sv = *(const s8v*)(s1b + (size_t)arow[r] * 128 + kb);
            union { s8v v; unsigned short u[8]; } o;
            #pragma unroll
            for (int u = 0; u < 4; ++u) {
                float h0 = fmaxf(fmaf(a0[u], bf2f((unsigned short)sv[u]), b0[u]), 0.f);
                float h1 = fmaxf(fmaf(a1[u], bf2f((unsigned short)sv[u + 4]), b1[u]), 0.f);
                o.u[u]     = f2bf(h0);
                o.u[u + 4] = f2bf(h1);
            }
            af[r] = o.v;
        }
        #pragma unroll
        for (int c = 0; c < 4; ++c)
            bfr[c] = *(const s8v*)(wB2p + (size_t)brow[c] * 128 + kb);
        #pragma unroll
        for (int r = 0; r < 4; ++r)
            #pragma unroll
            for (int c = 0; c < 4; ++c)
                acc[r][c] = __builtin_amdgcn_mfma_f32_16x16x32_bf16(af[r], bfr[c], acc[r][c], 0, 0, 0);
    }

    // epilogue: y2b bf16 stride 64 (j<47) / rbuf fp32 stride 48 + b2l (j 47..93)
    #pragma unroll
    for (int c = 0; c < 4; ++c) {
        int col = wc0 + c * 16 + lm;
        float bb = (col >= 47 && col < 94) ? b2l[col - 47] : 0.f;
        #pragma unroll
        for (int r = 0; r < 4; ++r) {
            int rowb = wr0 + r * 16 + q * 4;
            #pragma unroll
            for (int i = 0; i < 4; ++i) {
                int gr = r0 + rowb + i;
                if (gr >= n) continue;
                float v = acc[r][c][i];
                if (col < 47)      y2b[(size_t)gr * 64 + col] = f2bf(v);
                else if (col < 94) rbuf[(size_t)gr * 48 + (col - 47)] = v + bb;
            }
        }
    }
}

// ---- layer-2 gather + combine + L2-norm. 16 lanes/node (lane owns 4 ch),
// 16 nodes/block, 8-edge unroll -> 4 independent load chains per wave.
__global__ __launch_bounds__(256) void k_gather2_final(
        const unsigned short* __restrict__ y2b, const float* __restrict__ rbuf,
        const int* __restrict__ rowStart, const int* __restrict__ deg,
        const int* __restrict__ srcIdx, float* __restrict__ out, int n) {
    int t = threadIdx.x;
    int q = t & 15, grp = t >> 4;
    int node = blockIdx.x * 16 + grp;
    if (node >= n) return;
    int beg = rowStart[node];
    int d = deg[node];
    int end = beg + d;
    float acc[4] = {0.f, 0.f, 0.f, 0.f};
    int e = beg;
    for (; e + 8 <= end; e += 8) {
        int s0 = srcIdx[e],     s1v = srcIdx[e + 1];
        int s2 = srcIdx[e + 2], s3  = srcIdx[e + 3];
        int s4 = srcIdx[e + 4], s5  = srcIdx[e + 5];
        int s6 = srcIdx[e + 6], s7  = srcIdx[e + 7];
        s4v v0 = *(const s4v*)(y2b + (size_t)s0 * 64 + q * 4);
        s4v v1 = *(const s4v*)(y2b + (size_t)s1v * 64 + q * 4);
        s4v v2 = *(const s4v*)(y2b + (size_t)s2 * 64 + q * 4);
        s4v v3 = *(const s4v*)(y2b + (size_t)s3 * 64 + q * 4);
        s4v v4 = *(const s4v*)(y2b + (size_t)s4 * 64 + q * 4);
        s4v v5 = *(const s4v*)(y2b + (size_t)s5 * 64 + q * 4);
        s4v v6 = *(const s4v*)(y2b + (size_t)s6 * 64 + q * 4);
        s4v v7 = *(const s4v*)(y2b + (size_t)s7 * 64 + q * 4);
        #pragma unroll
        for (int u = 0; u < 4; ++u) {
            acc[u] += (bf2f((unsigned short)v0[u]) + bf2f((unsigned short)v1[u]))
                    + (bf2f((unsigned short)v2[u]) + bf2f((unsigned short)v3[u]))
                    + (bf2f((unsigned short)v4[u]) + bf2f((unsigned short)v5[u]))
                    + (bf2f((unsigned short)v6[u]) + bf2f((unsigned short)v7[u]));
        }
    }
    for (; e + 4 <= end; e += 4) {
        int s0 = srcIdx[e],     s1v = srcIdx[e + 1];
        int s2 = srcIdx[e + 2], s3  = srcIdx[e + 3];
        s4v v0 = *(const s4v*)(y2b + (size_t)s0 * 64 + q * 4);
        s4v v1 = *(const s4v*)(y2b + (size_t)s1v * 64 + q * 4);
        s4v v2 = *(const s4v*)(y2b + (size_t)s2 * 64 + q * 4);
        s4v v3 = *(const s4v*)(y2b + (size_t)s3 * 64 + q * 4);
        #pragma unroll
        for (int u = 0; u < 4; ++u)
            acc[u] += (bf2f((unsigned short)v0[u]) + bf2f((unsigned short)v1[u]))
                    + (bf2f((unsigned short)v2[u]) + bf2f((unsigned short)v3[u]));
    }
    for (; e < end; ++e) {
        s4v v0 = *(const s4v*)(y2b + (size_t)srcIdx[e] * 64 + q * 4);
        #pragma unroll
        for (int u = 0; u < 4; ++u) acc[u] += bf2f((unsigned short)v0[u]);
    }
    float ic = 1.0f / fmaxf((float)d, 1.0f);
    fx4 rb = *(const fx4*)(rbuf + (size_t)node * 48 + q * 4);
    float vi[4];
    float ss = 0.f;
    #pragma unroll
    for (int u = 0; u < 4; ++u) {
        int ch = q * 4 + u;
        float v = (ch < 47) ? (acc[u] * ic + rb[u]) : 0.f;   // select masks pad (NaN-safe)
        vi[u] = v;
        ss += v * v;
    }
    #pragma unroll
    for (int off = 1; off <= 8; off <<= 1) ss += __shfl_xor(ss, off, 64);
    float inv = 1.0f / fmaxf(sqrtf(ss), 1e-12f);
    #pragma unroll
    for (int u = 0; u < 4; ++u) {
        int ch = q * 4 + u;
        if (ch < 47) out[(size_t)node * 47 + ch] = vi[u] * inv;
    }
}

extern "C" void kernel_launch(void* const* d_in, const int* in_sizes, int n_in,
                              void* d_out, int out_size, void* d_ws, size_t ws_size,
                              hipStream_t stream) {
    const float* x     = (const float*)d_in[0];
    const int*   ei    = (const int*)d_in[1];
    const float* w1l   = (const float*)d_in[2];
    const float* b1l   = (const float*)d_in[3];
    const float* w1r   = (const float*)d_in[4];
    const float* gamma = (const float*)d_in[5];
    const float* beta  = (const float*)d_in[6];
    const float* w2l   = (const float*)d_in[7];
    const float* b2l   = (const float*)d_in[8];
    const float* w2r   = (const float*)d_in[9];
    float* out = (float*)d_out;

    int n  = in_sizes[0] / 128;   // 100000
    int nE = in_sizes[1] / 2;     // 800000

    int NB  = (n + 255) >> 8;                    // 391 buckets
    int nCh = (nE + CSR_CHUNK - 1) / CSR_CHUNK;  // 98 chunks

    // ---- workspace layout ----
    // deg[n](int) | stats[256](f32) | rowStart[n] | meta[n] | srcIdx[nE]
    // | xb[128n bf16] | aggb[128n bf16] | s1b[128n bf16] | wB1 | wB2p
    // meta: counts[nCh*512] then bucketStart at +60000, gcur[512] at +61000.
    // pairs[nE] overlays s1b (dead until gemm1).
    // y2b[64n bf16, 1 line/row] + rbuf[48n f32] overlay xb+aggb.
    int* deg       = (int*)d_ws;
    float* stats   = (float*)(deg + n);
    int* rowStart  = (int*)(stats + 256);
    int* meta      = rowStart + n;
    int* srcIdx    = meta + n;
    unsigned short* xb   = (unsigned short*)(srcIdx + nE);
    unsigned short* aggb = xb + (size_t)n * 128;
    unsigned short* s1b  = aggb + (size_t)n * 128;
    unsigned short* wB1  = s1b + (size_t)n * 128;
    unsigned short* wB2p = wB1 + 32768;
    int* counts      = meta;
    int* bucketStart = meta + 60000;
    int* gcur        = meta + 61000;
    int* pairs       = (int*)s1b;             // packed (src<<8)|(dst&255)
    unsigned short* y2b = xb;                 // stride 64 shorts (128B/row)
    float* rbuf = (float*)(y2b + (size_t)n * 64);   // stride 48 f32

    int prepTotal  = n * 16 + 32768 + 16384 + 256;
    int prepBlocks = (prepTotal + 255) / 256;

    // 1: prep (xcast | weight casts | stats zero | bcount histograms)
    k_prep<<<prepBlocks + nCh, 256, 0, stream>>>(
        x, w1l, w1r, w2l, w2r, ei, xb, wB1, wB2p, stats, counts, n, nE, prepBlocks);
    // 2-4: CSR build (bucketed counting sort, runtime range reservation)
    k_bmeta<<<1, 256, 0, stream>>>(counts, bucketStart, gcur, nCh, NB);
    k_bfill<<<nCh, 256, 0, stream>>>(ei, counts, gcur, pairs, nE);
    k_csr<<<NB, 256, 0, stream>>>(pairs, bucketStart, deg, rowStart, srcIdx, n);
    // 5-6: layer 1
    k_gather1<<<(n + 15) / 16, 256, 0, stream>>>(xb, rowStart, deg, srcIdx, aggb, n);
    k_gemm1<<<(n + 127) / 128, 256, 0, stream>>>(xb, aggb, wB1, b1l, s1b, stats, n);
    // 7-8: layer 2 (BN finalize inlined in gemm2)
    k_gemm2<<<(n + 127) / 128, 256, 0, stream>>>(
        s1b, wB2p, stats, gamma, beta, b2l, y2b, rbuf, n);
    k_gather2_final<<<(n + 15) / 16, 256, 0, stream>>>(y2b, rbuf, rowStart, deg, srcIdx, out, n);
}

// Round 7
// 291.822 us; speedup vs baseline: 1.0235x; 1.0235x over previous
//
#include <hip/hip_runtime.h>
#include <cstdint>

// GNN: 2-layer GraphSAGE (mean aggr, L2-normalize) + BatchNorm(train) + ReLU.
// N=100000 nodes, E=800000 edges, C: 128 -> 128 -> 47.
//
// Round 17: R16's direct-from-global GEMM regressed (52.8us vs R15's 40.4):
// fragment loads scatter 64 lanes over 16 rows x 64B at 256B stride -> 16
// cache-line transactions/instruction; VMEM issue cost > barrier savings.
// Revert to R15 GEMM base and remove the REAL cost instead: R15 paid 8
// serial vmcnt(0)+barrier rounds per block. The whole K=256 panel fits LDS:
//  - gemm1: stage A-panel (128x256, 64KB: aggb cols 0..127 | xb cols 128..255)
//    + full weight matrix (64KB) ONCE (32 DMAs/thread in flight), ONE
//    __syncthreads, then 64 MFMAs/wave with zero further barriers.
//  - gemm2: same, 32KB+32KB -> 2 blocks/CU.
// XOR slot swizzle re-derived for new row strides: phys16Bslot = slot^(row&7)
// on BOTH global source and ds_read (8 bank-groups x 8 lanes -- the exact
// pattern that measured 0 conflicts in R15). Sync: only __syncthreads().
// Rest unchanged from R15 (passed, 270.1us).

typedef __attribute__((ext_vector_type(8))) short s8v;
typedef __attribute__((ext_vector_type(4))) short s4v;
typedef __attribute__((ext_vector_type(4))) float fx4;

#define CSR_CHUNK 8192
#define CSR_SH 8            // 256 nodes per bucket
#define CSR_NBPAD 512       // padded bucket count (NB = ceil(n/256) = 391)
#define CSR_BUFCAP 3072     // LDS srcbuf cap per bucket (mean 2046, +20 sigma)

static __device__ __forceinline__ float bf2f(unsigned short h) {
    union { unsigned int u; float f; } c; c.u = (unsigned int)h << 16; return c.f;
}
static __device__ __forceinline__ unsigned short f2bf(float f) {
    union { float f; unsigned int u; } c; c.f = f;
    unsigned int u = c.u;
    return (unsigned short)((u + 0x7FFF + ((u >> 16) & 1)) >> 16);   // RNE
}

// ---- merged prep: x->bf16 | weight casts | stats zero | bcount histograms.
__global__ __launch_bounds__(256) void k_prep(
        const float* __restrict__ x, const float* __restrict__ w1l,
        const float* __restrict__ w1r, const float* __restrict__ w2l,
        const float* __restrict__ w2r, const int* __restrict__ ei,
        unsigned short* __restrict__ xb, unsigned short* __restrict__ wB1,
        unsigned short* __restrict__ wB2p, float* __restrict__ stats,
        int* __restrict__ counts, int n, int nE, int prepBlocks) {
    __shared__ int hist[CSR_NBPAD];
    int t = threadIdx.x;
    if ((int)blockIdx.x >= prepBlocks) {
        int chunk = blockIdx.x - prepBlocks;
        hist[t] = 0; hist[t + 256] = 0;
        __syncthreads();
        int e0 = chunk * CSR_CHUNK;
        int e1 = min(e0 + CSR_CHUNK, nE);
        for (int e = e0 + t; e < e1; e += 256)
            atomicAdd(&hist[ei[nE + e] >> CSR_SH], 1);
        __syncthreads();
        counts[chunk * CSR_NBPAD + t] = hist[t];
        counts[chunk * CSR_NBPAD + t + 256] = hist[t + 256];
        return;
    }
    int idx = blockIdx.x * 256 + t;
    int nx = n * 16;
    if (idx < nx) {
        float4 a = ((const float4*)x)[idx * 2];
        float4 b = ((const float4*)x)[idx * 2 + 1];
        union { s8v v; unsigned short u[8]; } o;
        o.u[0] = f2bf(a.x); o.u[1] = f2bf(a.y); o.u[2] = f2bf(a.z); o.u[3] = f2bf(a.w);
        o.u[4] = f2bf(b.x); o.u[5] = f2bf(b.y); o.u[6] = f2bf(b.z); o.u[7] = f2bf(b.w);
        ((s8v*)xb)[idx] = o.v;
        return;
    }
    idx -= nx;
    if (idx < 32768) {
        int j = idx >> 8, k = idx & 255;
        float v = (k < 128) ? w1l[j * 128 + k] : w1r[j * 128 + (k - 128)];
        wB1[idx] = f2bf(v);
        return;
    }
    idx -= 32768;
    if (idx < 16384) {
        int j = idx >> 7, k = idx & 127;
        float v = 0.f;
        if (j < 47)      v = w2l[j * 128 + k];
        else if (j < 94) v = w2r[(j - 47) * 128 + k];
        wB2p[idx] = f2bf(v);
        return;
    }
    idx -= 16384;
    if (idx < 256) stats[idx] = 0.f;
}

// ---- CSR build: bucketed counting sort -------------------------------
__global__ __launch_bounds__(256) void k_bmeta(
        const int* __restrict__ counts, int* __restrict__ bucketStart,
        int* __restrict__ gcur, int nCh, int NB) {
    __shared__ int tot[CSR_NBPAD], tot2[CSR_NBPAD], sh[256], bs[CSR_NBPAD];
    int t = threadIdx.x;
    int tl = t & 127, g = t >> 7;
    int half = (nCh + 1) >> 1;
    int c0 = g * half, c1 = min(nCh, c0 + half);
    int4 s4 = {0, 0, 0, 0};
    for (int c = c0; c < c1; ++c) {
        int4 v = *(const int4*)(counts + (size_t)c * CSR_NBPAD + tl * 4);
        s4.x += v.x; s4.y += v.y; s4.z += v.z; s4.w += v.w;
    }
    *(int4*)((g ? tot2 : tot) + tl * 4) = s4;
    __syncthreads();
    tot[t] += tot2[t];
    tot[t + 256] += tot2[t + 256];
    __syncthreads();
    int pairSum = tot[2 * t] + tot[2 * t + 1];
    sh[t] = pairSum;
    __syncthreads();
    for (int off = 1; off < 256; off <<= 1) {
        int add = (t >= off) ? sh[t - off] : 0;
        __syncthreads();
        sh[t] += add;
        __syncthreads();
    }
    int excl = sh[t] - pairSum;
    bs[2 * t] = excl;
    bs[2 * t + 1] = excl + tot[2 * t];
    __syncthreads();
    for (int b = t; b <= NB; b += 256) bucketStart[b] = bs[b];
    for (int b = t; b < CSR_NBPAD; b += 256) gcur[b] = bs[b];
}

__global__ __launch_bounds__(256) void k_bfill(
        const int* __restrict__ ei, const int* __restrict__ counts,
        int* __restrict__ gcur, int* __restrict__ pairs, int nE) {
    __shared__ int cur[CSR_NBPAD];
    int t = threadIdx.x;
    #pragma unroll
    for (int i = 0; i < 2; ++i) {
        int b = t + i * 256;
        int h = counts[blockIdx.x * CSR_NBPAD + b];
        cur[b] = h ? atomicAdd(&gcur[b], h) : 0;
    }
    __syncthreads();
    int e0 = blockIdx.x * CSR_CHUNK;
    int e1 = min(e0 + CSR_CHUNK, nE);
    for (int e = e0 + t; e < e1; e += 256) {
        int s = ei[e];
        int d = ei[nE + e];
        int p = atomicAdd(&cur[d >> CSR_SH], 1);
        pairs[p] = (s << 8) | (d & 255);
    }
}

__global__ __launch_bounds__(256) void k_csr(
        const int* __restrict__ pairs, const int* __restrict__ bucketStart,
        int* __restrict__ deg, int* __restrict__ rowStart,
        int* __restrict__ srcIdx, int n) {
    __shared__ int cnt[256], scn[256], cur[256];
    __shared__ int buf[CSR_BUFCAP];
    int t = threadIdx.x;
    int bkt = blockIdx.x;
    int eBeg = bucketStart[bkt], eEnd = bucketStart[bkt + 1];
    int node0 = bkt << CSR_SH;
    cnt[t] = 0;
    __syncthreads();
    for (int e = eBeg + t; e < eEnd; e += 256)
        atomicAdd(&cnt[pairs[e] & 255], 1);
    __syncthreads();
    int myc = cnt[t];
    scn[t] = myc;
    __syncthreads();
    for (int off = 1; off < 256; off <<= 1) {
        int add = (t >= off) ? scn[t - off] : 0;
        __syncthreads();
        scn[t] += add;
        __syncthreads();
    }
    int excl = scn[t] - myc;
    cur[t] = excl;
    int node = node0 + t;
    if (node < n) { deg[node] = myc; rowStart[node] = eBeg + excl; }
    __syncthreads();
    for (int e = eBeg + t; e < eEnd; e += 256) {
        int pk = pairs[e];
        int p = atomicAdd(&cur[pk & 255], 1);
        int src = pk >> 8;
        if (p < CSR_BUFCAP) buf[p] = src;
        else srcIdx[eBeg + p] = src;   // statistically never at this size
    }
    __syncthreads();
    int m = min(eEnd - eBeg, CSR_BUFCAP);
    for (int i = t; i < m; i += 256) srcIdx[eBeg + i] = buf[i];
}

// ---- layer-1 gather (bf16): 16 lanes/node, lane owns 8 ch; 4-edge unroll.
__global__ __launch_bounds__(256) void k_gather1(
        const unsigned short* __restrict__ xb, const int* __restrict__ rowStart,
        const int* __restrict__ deg, const int* __restrict__ srcIdx,
        unsigned short* __restrict__ aggb, int n) {
    int t = threadIdx.x;
    int q = t & 15, grp = t >> 4;
    int node = blockIdx.x * 16 + grp;
    if (node >= n) return;
    int beg = rowStart[node];
    int d = deg[node];
    int end = beg + d;
    float a0[8] = {}, a1[8] = {}, a2[8] = {}, a3[8] = {};
    int e = beg;
    for (; e + 4 <= end; e += 4) {
        int s0 = srcIdx[e], s1v = srcIdx[e + 1], s2 = srcIdx[e + 2], s3 = srcIdx[e + 3];
        s8v v0 = *(const s8v*)(xb + (size_t)s0 * 128 + q * 8);
        s8v v1 = *(const s8v*)(xb + (size_t)s1v * 128 + q * 8);
        s8v v2 = *(const s8v*)(xb + (size_t)s2 * 128 + q * 8);
        s8v v3 = *(const s8v*)(xb + (size_t)s3 * 128 + q * 8);
        #pragma unroll
        for (int u = 0; u < 8; ++u) {
            a0[u] += bf2f((unsigned short)v0[u]);
            a1[u] += bf2f((unsigned short)v1[u]);
            a2[u] += bf2f((unsigned short)v2[u]);
            a3[u] += bf2f((unsigned short)v3[u]);
        }
    }
    for (; e < end; ++e) {
        s8v v0 = *(const s8v*)(xb + (size_t)srcIdx[e] * 128 + q * 8);
        #pragma unroll
        for (int u = 0; u < 8; ++u) a0[u] += bf2f((unsigned short)v0[u]);
    }
    float ic = 1.0f / fmaxf((float)d, 1.0f);
    union { s8v v; unsigned short u[8]; } o;
    #pragma unroll
    for (int u = 0; u < 8; ++u)
        o.u[u] = f2bf((a0[u] + a1[u] + a2[u] + a3[u]) * ic);
    *(s8v*)(aggb + (size_t)node * 128 + q * 8) = o.v;
}

// Async 16B global->LDS (gfx950). Dest is wave-uniform base + lane*16;
// our LDS layout is lane-linear so per-lane dest == HW dest.
#define GLL16(GSRC, LDST) \
    __builtin_amdgcn_global_load_lds( \
        (__attribute__((address_space(1))) void*)(void*)(GSRC), \
        (__attribute__((address_space(3))) void*)(LDST), 16, 0, 0)

// ---- GEMM1 (bf16 MFMA): block 128x128, K=256 (aggb cols 0..127 | xb
// 128..255). One-shot panel stage: 64KB A + 64KB W in LDS, ONE barrier,
// then 64 MFMAs/wave barrier-free. Swizzle: phys 16B slot = slot^(row&7)
// on both global source and ds_read.
__global__ __launch_bounds__(256, 1) void k_gemm1(
        const unsigned short* __restrict__ xb, const unsigned short* __restrict__ aggb,
        const unsigned short* __restrict__ wB1, const float* __restrict__ b1l,
        unsigned short* __restrict__ s1b, float* __restrict__ stats, int n) {
    __shared__ __align__(16) unsigned short xs[128 * 256];  // 64KB [row][256]
    __shared__ __align__(16) unsigned short ws[128 * 256];  // 64KB [j][256]
    __shared__ float norm2[256];   // [128][2]
    __shared__ float invn[128];
    __shared__ float statS[256];   // [128][2]
    __shared__ float statQ[256];   // [128][2]
    int t = threadIdx.x;
    int w = t >> 6, L = t & 63;
    int q = L >> 4, lm = L & 15;
    int wr0 = (w >> 1) * 64;     // wave row base
    int wc0 = (w & 1) * 64;      // wave col base
    int r0 = blockIdx.x * 128;

    // stage: 4096 16B chunks each for xs and ws; 32 DMAs/thread in flight.
    for (int i = t; i < 4096; i += 256) {
        int row = i >> 5, p = i & 31;
        int sl = p ^ (row & 7);              // logical 16B slot at phys p
        int gr = r0 + row; gr = gr < n ? gr : (n - 1);
        const unsigned short* sp = (sl < 16) ? (aggb + (size_t)gr * 128 + sl * 8)
                                             : (xb + (size_t)gr * 128 + (sl - 16) * 8);
        GLL16(sp, &xs[i * 8]);
        GLL16(wB1 + (size_t)row * 256 + sl * 8, &ws[i * 8]);
    }
    __syncthreads();   // full vmcnt(0)+lgkmcnt(0) drain -> panel visible

    fx4 acc[4][4];
    fx4 z4 = {0.f, 0.f, 0.f, 0.f};
    #pragma unroll
    for (int r = 0; r < 4; ++r)
        #pragma unroll
        for (int c = 0; c < 4; ++c) acc[r][c] = z4;

    #pragma unroll
    for (int kt = 0; kt < 8; ++kt) {
        int slot = kt * 4 + q;
        s8v af[4], bfr[4];
        #pragma unroll
        for (int r = 0; r < 4; ++r) {
            int row = wr0 + r * 16 + lm;
            af[r] = *(const s8v*)&xs[row * 256 + ((slot ^ (row & 7)) << 3)];
        }
        #pragma unroll
        for (int c = 0; c < 4; ++c) {
            int row = wc0 + c * 16 + lm;
            bfr[c] = *(const s8v*)&ws[row * 256 + ((slot ^ (row & 7)) << 3)];
        }
        #pragma unroll
        for (int r = 0; r < 4; ++r)
            #pragma unroll
            for (int c = 0; c < 4; ++c)
                acc[r][c] = __builtin_amdgcn_mfma_f32_16x16x32_bf16(af[r], bfr[c], acc[r][c], 0, 0, 0);
    }

    // ---- epilogue: bias -> row L2-norm -> scale -> bf16 store -> BN stats
    float bj[4];
    #pragma unroll
    for (int c = 0; c < 4; ++c) bj[c] = b1l[wc0 + c * 16 + lm];
    #pragma unroll
    for (int r = 0; r < 4; ++r)
        #pragma unroll
        for (int c = 0; c < 4; ++c) acc[r][c] += bj[c];

    fx4 pr[4];
    #pragma unroll
    for (int r = 0; r < 4; ++r) {
        fx4 p = acc[r][0] * acc[r][0];
        #pragma unroll
        for (int c = 1; c < 4; ++c) p += acc[r][c] * acc[r][c];
        #pragma unroll
        for (int off = 1; off <= 8; off <<= 1)
            #pragma unroll
            for (int i2 = 0; i2 < 4; ++i2) p[i2] += __shfl_xor(p[i2], off, 64);
        pr[r] = p;
    }

    if (lm == 0) {
        #pragma unroll
        for (int r = 0; r < 4; ++r)
            #pragma unroll
            for (int i = 0; i < 4; ++i)
                norm2[(wr0 + r * 16 + q * 4 + i) * 2 + (w & 1)] = pr[r][i];
    }
    __syncthreads();
    if (t < 128) {
        float s = norm2[t * 2] + norm2[t * 2 + 1];
        invn[t] = 1.0f / fmaxf(sqrtf(s), 1e-12f);
    }
    __syncthreads();

    float cS[4] = {}, cQ[4] = {};
    #pragma unroll
    for (int r = 0; r < 4; ++r) {
        int rowb = wr0 + r * 16 + q * 4;
        fx4 iv = *(const fx4*)&invn[rowb];
        #pragma unroll
        for (int c = 0; c < 4; ++c) {
            fx4 v = acc[r][c] * iv;
            int col = wc0 + c * 16 + lm;
            #pragma unroll
            for (int i = 0; i < 4; ++i) {
                int gr = r0 + rowb + i;
                if (gr < n) {
                    s1b[(size_t)gr * 128 + col] = f2bf(v[i]);
                    cS[c] += v[i];
                    cQ[c] += v[i] * v[i];
                }
            }
        }
    }
    #pragma unroll
    for (int off = 16; off <= 32; off <<= 1)
        #pragma unroll
        for (int c = 0; c < 4; ++c) {
            cS[c] += __shfl_xor(cS[c], off, 64);
            cQ[c] += __shfl_xor(cQ[c], off, 64);
        }
    if (q == 0) {
        #pragma unroll
        for (int c = 0; c < 4; ++c) {
            int col = wc0 + c * 16 + lm;
            statS[col * 2 + (w >> 1)] = cS[c];
            statQ[col * 2 + (w >> 1)] = cQ[c];
        }
    }
    __syncthreads();
    if (t < 128) {
        atomicAdd(&stats[t],       statS[t * 2] + statS[t * 2 + 1]);
        atomicAdd(&stats[128 + t], statQ[t * 2] + statQ[t * 2 + 1]);
    }
}

// ---- GEMM2 (bf16 MFMA) with inline BN finalize. One-shot panel stage
// (32KB+32KB, 2 blocks/CU), BN+ReLU applied to A-fragment after ds_read.
__global__ __launch_bounds__(256, 2) void k_gemm2(
        const unsigned short* __restrict__ s1b, const unsigned short* __restrict__ wB2p,
        const float* __restrict__ stats, const float* __restrict__ gamma,
        const float* __restrict__ beta, const float* __restrict__ b2l,
        unsigned short* __restrict__ y2b, float* __restrict__ rbuf, int n) {
    __shared__ __align__(16) unsigned short xs[128 * 128];  // 32KB
    __shared__ __align__(16) unsigned short ws[128 * 128];  // 32KB
    __shared__ __align__(16) float abuf[128];
    __shared__ __align__(16) float bbuf[128];
    int t = threadIdx.x;
    int w = t >> 6, L = t & 63;
    int q = L >> 4, lm = L & 15;
    int wr0 = (w >> 1) * 64, wc0 = (w & 1) * 64;
    int r0 = blockIdx.x * 128;

    if (t < 128) {
        float s = stats[t], qv = stats[128 + t];
        float fn = (float)n;
        float mean = s / fn;
        float var = qv / fn - mean * mean;   // biased variance
        float istd = rsqrtf(var + 1e-5f);
        float a = gamma[t] * istd;
        abuf[t] = a;
        bbuf[t] = beta[t] - mean * a;
    }

    // stage: 2048 16B chunks each; 16 DMAs/thread.
    for (int i = t; i < 2048; i += 256) {
        int row = i >> 4, p = i & 15;
        int sl = p ^ (row & 7);
        int gr = r0 + row; gr = gr < n ? gr : (n - 1);
        GLL16(s1b + (size_t)gr * 128 + sl * 8, &xs[i * 8]);
        GLL16(wB2p + (size_t)row * 128 + sl * 8, &ws[i * 8]);
    }
    __syncthreads();   // drain: panel + abuf/bbuf visible

    fx4 acc[4][4];
    fx4 z4 = {0.f, 0.f, 0.f, 0.f};
    #pragma unroll
    for (int r = 0; r < 4; ++r)
        #pragma unroll
        for (int c = 0; c < 4; ++c) acc[r][c] = z4;

    #pragma unroll
    for (int kt = 0; kt < 4; ++kt) {
        int slot = kt * 4 + q;
        int kb = kt * 32 + q * 8;
        fx4 a0 = *(const fx4*)&abuf[kb];
        fx4 a1 = *(const fx4*)&abuf[kb + 4];
        fx4 b0 = *(const fx4*)&bbuf[kb];
        fx4 b1 = *(const fx4*)&bbuf[kb + 4];
        s8v af[4], bfr[4];
        #pragma unroll
        for (int r = 0; r < 4; ++r) {
            int row = wr0 + r * 16 + lm;
            s8v sv = *(const s8v*)&xs[row * 128 + ((slot ^ (row & 7)) << 3)];
            union { s8v v; unsigned short u[8]; } o;
            #pragma unroll
            for (int u = 0; u < 4; ++u) {
                float h0 = fmaxf(fmaf(a0[u], bf2f((unsigned short)sv[u]), b0[u]), 0.f);
                float h1 = fmaxf(fmaf(a1[u], bf2f((unsigned short)sv[u + 4]), b1[u]), 0.f);
                o.u[u]     = f2bf(h0);
                o.u[u + 4] = f2bf(h1);
            }
            af[r] = o.v;
        }
        #pragma unroll
        for (int c = 0; c < 4; ++c) {
            int row = wc0 + c * 16 + lm;
            bfr[c] = *(const s8v*)&ws[row * 128 + ((slot ^ (row & 7)) << 3)];
        }
        #pragma unroll
        for (int r = 0; r < 4; ++r)
            #pragma unroll
            for (int c = 0; c < 4; ++c)
                acc[r][c] = __builtin_amdgcn_mfma_f32_16x16x32_bf16(af[r], bfr[c], acc[r][c], 0, 0, 0);
    }

    // epilogue: y2b bf16 stride 64 (j<47) / rbuf fp32 stride 48 + b2l (j 47..93)
    #pragma unroll
    for (int c = 0; c < 4; ++c) {
        int col = wc0 + c * 16 + lm;
        float bb = (col >= 47 && col < 94) ? b2l[col - 47] : 0.f;
        #pragma unroll
        for (int r = 0; r < 4; ++r) {
            int rowb = wr0 + r * 16 + q * 4;
            #pragma unroll
            for (int i = 0; i < 4; ++i) {
                int gr = r0 + rowb + i;
                if (gr >= n) continue;
                float v = acc[r][c][i];
                if (col < 47)      y2b[(size_t)gr * 64 + col] = f2bf(v);
                else if (col < 94) rbuf[(size_t)gr * 48 + (col - 47)] = v + bb;
            }
        }
    }
}

// ---- layer-2 gather + combine + L2-norm. 16 lanes/node (lane owns 4 ch),
// 16 nodes/block, 8-edge unroll -> 4 independent load chains per wave.
__global__ __launch_bounds__(256) void k_gather2_final(
        const unsigned short* __restrict__ y2b, const float* __restrict__ rbuf,
        const int* __restrict__ rowStart, const int* __restrict__ deg,
        const int* __restrict__ srcIdx, float* __restrict__ out, int n) {
    int t = threadIdx.x;
    int q = t & 15, grp = t >> 4;
    int node = blockIdx.x * 16 + grp;
    if (node >= n) return;
    int beg = rowStart[node];
    int d = deg[node];
    int end = beg + d;
    float acc[4] = {0.f, 0.f, 0.f, 0.f};
    int e = beg;
    for (; e + 8 <= end; e += 8) {
        int s0 = srcIdx[e],     s1v = srcIdx[e + 1];
        int s2 = srcIdx[e + 2], s3  = srcIdx[e + 3];
        int s4 = srcIdx[e + 4], s5  = srcIdx[e + 5];
        int s6 = srcIdx[e + 6], s7  = srcIdx[e + 7];
        s4v v0 = *(const s4v*)(y2b + (size_t)s0 * 64 + q * 4);
        s4v v1 = *(const s4v*)(y2b + (size_t)s1v * 64 + q * 4);
        s4v v2 = *(const s4v*)(y2b + (size_t)s2 * 64 + q * 4);
        s4v v3 = *(const s4v*)(y2b + (size_t)s3 * 64 + q * 4);
        s4v v4 = *(const s4v*)(y2b + (size_t)s4 * 64 + q * 4);
        s4v v5 = *(const s4v*)(y2b + (size_t)s5 * 64 + q * 4);
        s4v v6 = *(const s4v*)(y2b + (size_t)s6 * 64 + q * 4);
        s4v v7 = *(const s4v*)(y2b + (size_t)s7 * 64 + q * 4);
        #pragma unroll
        for (int u = 0; u < 4; ++u) {
            acc[u] += (bf2f((unsigned short)v0[u]) + bf2f((unsigned short)v1[u]))
                    + (bf2f((unsigned short)v2[u]) + bf2f((unsigned short)v3[u]))
                    + (bf2f((unsigned short)v4[u]) + bf2f((unsigned short)v5[u]))
                    + (bf2f((unsigned short)v6[u]) + bf2f((unsigned short)v7[u]));
        }
    }
    for (; e + 4 <= end; e += 4) {
        int s0 = srcIdx[e],     s1v = srcIdx[e + 1];
        int s2 = srcIdx[e + 2], s3  = srcIdx[e + 3];
        s4v v0 = *(const s4v*)(y2b + (size_t)s0 * 64 + q * 4);
        s4v v1 = *(const s4v*)(y2b + (size_t)s1v * 64 + q * 4);
        s4v v2 = *(const s4v*)(y2b + (size_t)s2 * 64 + q * 4);
        s4v v3 = *(const s4v*)(y2b + (size_t)s3 * 64 + q * 4);
        #pragma unroll
        for (int u = 0; u < 4; ++u)
            acc[u] += (bf2f((unsigned short)v0[u]) + bf2f((unsigned short)v1[u]))
                    + (bf2f((unsigned short)v2[u]) + bf2f((unsigned short)v3[u]));
    }
    for (; e < end; ++e) {
        s4v v0 = *(const s4v*)(y2b + (size_t)srcIdx[e] * 64 + q * 4);
        #pragma unroll
        for (int u = 0; u < 4; ++u) acc[u] += bf2f((unsigned short)v0[u]);
    }
    float ic = 1.0f / fmaxf((float)d, 1.0f);
    fx4 rb = *(const fx4*)(rbuf + (size_t)node * 48 + q * 4);
    float vi[4];
    float ss = 0.f;
    #pragma unroll
    for (int u = 0; u < 4; ++u) {
        int ch = q * 4 + u;
        float v = (ch < 47) ? (acc[u] * ic + rb[u]) : 0.f;   // select masks pad (NaN-safe)
        vi[u] = v;
        ss += v * v;
    }
    #pragma unroll
    for (int off = 1; off <= 8; off <<= 1) ss += __shfl_xor(ss, off, 64);
    float inv = 1.0f / fmaxf(sqrtf(ss), 1e-12f);
    #pragma unroll
    for (int u = 0; u < 4; ++u) {
        int ch = q * 4 + u;
        if (ch < 47) out[(size_t)node * 47 + ch] = vi[u] * inv;
    }
}

extern "C" void kernel_launch(void* const* d_in, const int* in_sizes, int n_in,
                              void* d_out, int out_size, void* d_ws, size_t ws_size,
                              hipStream_t stream) {
    const float* x     = (const float*)d_in[0];
    const int*   ei    = (const int*)d_in[1];
    const float* w1l   = (const float*)d_in[2];
    const float* b1l   = (const float*)d_in[3];
    const float* w1r   = (const float*)d_in[4];
    const float* gamma = (const float*)d_in[5];
    const float* beta  = (const float*)d_in[6];
    const float* w2l   = (const float*)d_in[7];
    const float* b2l   = (const float*)d_in[8];
    const float* w2r   = (const float*)d_in[9];
    float* out = (float*)d_out;

    int n  = in_sizes[0] / 128;   // 100000
    int nE = in_sizes[1] / 2;     // 800000

    int NB  = (n + 255) >> 8;                    // 391 buckets
    int nCh = (nE + CSR_CHUNK - 1) / CSR_CHUNK;  // 98 chunks

    // ---- workspace layout ----
    // deg[n](int) | stats[256](f32) | rowStart[n] | meta[n] | srcIdx[nE]
    // | xb[128n bf16] | aggb[128n bf16] | s1b[128n bf16] | wB1 | wB2p
    // meta: counts[nCh*512] then bucketStart at +60000, gcur[512] at +61000.
    // pairs[nE] overlays s1b (dead until gemm1).
    // y2b[64n bf16, 1 line/row] + rbuf[48n f32] overlay xb+aggb.
    int* deg       = (int*)d_ws;
    float* stats   = (float*)(deg + n);
    int* rowStart  = (int*)(stats + 256);
    int* meta      = rowStart + n;
    int* srcIdx    = meta + n;
    unsigned short* xb   = (unsigned short*)(srcIdx + nE);
    unsigned short* aggb = xb + (size_t)n * 128;
    unsigned short* s1b  = aggb + (size_t)n * 128;
    unsigned short* wB1  = s1b + (size_t)n * 128;
    unsigned short* wB2p = wB1 + 32768;
    int* counts      = meta;
    int* bucketStart = meta + 60000;
    int* gcur        = meta + 61000;
    int* pairs       = (int*)s1b;             // packed (src<<8)|(dst&255)
    unsigned short* y2b = xb;                 // stride 64 shorts (128B/row)
    float* rbuf = (float*)(y2b + (size_t)n * 64);   // stride 48 f32

    int prepTotal  = n * 16 + 32768 + 16384 + 256;
    int prepBlocks = (prepTotal + 255) / 256;

    // 1: prep (xcast | weight casts | stats zero | bcount histograms)
    k_prep<<<prepBlocks + nCh, 256, 0, stream>>>(
        x, w1l, w1r, w2l, w2r, ei, xb, wB1, wB2p, stats, counts, n, nE, prepBlocks);
    // 2-4: CSR build (bucketed counting sort, runtime range reservation)
    k_bmeta<<<1, 256, 0, stream>>>(counts, bucketStart, gcur, nCh, NB);
    k_bfill<<<nCh, 256, 0, stream>>>(ei, counts, gcur, pairs, nE);
    k_csr<<<NB, 256, 0, stream>>>(pairs, bucketStart, deg, rowStart, srcIdx, n);
    // 5-6: layer 1
    k_gather1<<<(n + 15) / 16, 256, 0, stream>>>(xb, rowStart, deg, srcIdx, aggb, n);
    k_gemm1<<<(n + 127) / 128, 256, 0, stream>>>(xb, aggb, wB1, b1l, s1b, stats, n);
    // 7-8: layer 2 (BN finalize inlined in gemm2)
    k_gemm2<<<(n + 127) / 128, 256, 0, stream>>>(
        s1b, wB2p, stats, gamma, beta, b2l, y2b, rbuf, n);
    k_gather2_final<<<(n + 15) / 16, 256, 0, stream>>>(y2b, rbuf, rowStart, deg, srcIdx, out, n);
}

// Round 8
// 285.148 us; speedup vs baseline: 1.0474x; 1.0234x over previous
//
#include <hip/hip_runtime.h>
#include <cstdint>

// GNN: 2-layer GraphSAGE (mean aggr, L2-normalize) + BatchNorm(train) + ReLU.
// N=100000 nodes, E=800000 edges, C: 128 -> 128 -> 47.
//
// Round 18: R17's one-shot 128KB panel stage regressed (48.5us, occupancy 7%,
// 1 block/CU -> no cross-block overlap; 800K bank conflicts from the row&7
// swizzle at 512B stride). Revert to the R15 GEMM structure (40.4us, 0
// conflicts measured) and HALVE THE ROUND COUNT instead: BK=64 -- each round
// stages TWO 32-col subtiles, each byte-identical in layout to R15's proven
// subtile (stride-32 linear LDS, slot XOR p^((row>>1)&3) on both global
// source and ds_read), then computes 32 MFMAs/wave. gemm1: 8 rounds -> 4;
// gemm2: 4 -> 2. Sync unchanged: __syncthreads / stage / __syncthreads /
// compute. LDS 32KB/block, 3 blocks/CU. Rest unchanged from R15 (270.1us).

typedef __attribute__((ext_vector_type(8))) short s8v;
typedef __attribute__((ext_vector_type(4))) short s4v;
typedef __attribute__((ext_vector_type(4))) float fx4;

#define CSR_CHUNK 8192
#define CSR_SH 8            // 256 nodes per bucket
#define CSR_NBPAD 512       // padded bucket count (NB = ceil(n/256) = 391)
#define CSR_BUFCAP 3072     // LDS srcbuf cap per bucket (mean 2046, +20 sigma)

static __device__ __forceinline__ float bf2f(unsigned short h) {
    union { unsigned int u; float f; } c; c.u = (unsigned int)h << 16; return c.f;
}
static __device__ __forceinline__ unsigned short f2bf(float f) {
    union { float f; unsigned int u; } c; c.f = f;
    unsigned int u = c.u;
    return (unsigned short)((u + 0x7FFF + ((u >> 16) & 1)) >> 16);   // RNE
}

// ---- merged prep: x->bf16 | weight casts | stats zero | bcount histograms.
__global__ __launch_bounds__(256) void k_prep(
        const float* __restrict__ x, const float* __restrict__ w1l,
        const float* __restrict__ w1r, const float* __restrict__ w2l,
        const float* __restrict__ w2r, const int* __restrict__ ei,
        unsigned short* __restrict__ xb, unsigned short* __restrict__ wB1,
        unsigned short* __restrict__ wB2p, float* __restrict__ stats,
        int* __restrict__ counts, int n, int nE, int prepBlocks) {
    __shared__ int hist[CSR_NBPAD];
    int t = threadIdx.x;
    if ((int)blockIdx.x >= prepBlocks) {
        int chunk = blockIdx.x - prepBlocks;
        hist[t] = 0; hist[t + 256] = 0;
        __syncthreads();
        int e0 = chunk * CSR_CHUNK;
        int e1 = min(e0 + CSR_CHUNK, nE);
        for (int e = e0 + t; e < e1; e += 256)
            atomicAdd(&hist[ei[nE + e] >> CSR_SH], 1);
        __syncthreads();
        counts[chunk * CSR_NBPAD + t] = hist[t];
        counts[chunk * CSR_NBPAD + t + 256] = hist[t + 256];
        return;
    }
    int idx = blockIdx.x * 256 + t;
    int nx = n * 16;
    if (idx < nx) {
        float4 a = ((const float4*)x)[idx * 2];
        float4 b = ((const float4*)x)[idx * 2 + 1];
        union { s8v v; unsigned short u[8]; } o;
        o.u[0] = f2bf(a.x); o.u[1] = f2bf(a.y); o.u[2] = f2bf(a.z); o.u[3] = f2bf(a.w);
        o.u[4] = f2bf(b.x); o.u[5] = f2bf(b.y); o.u[6] = f2bf(b.z); o.u[7] = f2bf(b.w);
        ((s8v*)xb)[idx] = o.v;
        return;
    }
    idx -= nx;
    if (idx < 32768) {
        int j = idx >> 8, k = idx & 255;
        float v = (k < 128) ? w1l[j * 128 + k] : w1r[j * 128 + (k - 128)];
        wB1[idx] = f2bf(v);
        return;
    }
    idx -= 32768;
    if (idx < 16384) {
        int j = idx >> 7, k = idx & 127;
        float v = 0.f;
        if (j < 47)      v = w2l[j * 128 + k];
        else if (j < 94) v = w2r[(j - 47) * 128 + k];
        wB2p[idx] = f2bf(v);
        return;
    }
    idx -= 16384;
    if (idx < 256) stats[idx] = 0.f;
}

// ---- CSR build: bucketed counting sort -------------------------------
__global__ __launch_bounds__(256) void k_bmeta(
        const int* __restrict__ counts, int* __restrict__ bucketStart,
        int* __restrict__ gcur, int nCh, int NB) {
    __shared__ int tot[CSR_NBPAD], tot2[CSR_NBPAD], sh[256], bs[CSR_NBPAD];
    int t = threadIdx.x;
    int tl = t & 127, g = t >> 7;
    int half = (nCh + 1) >> 1;
    int c0 = g * half, c1 = min(nCh, c0 + half);
    int4 s4 = {0, 0, 0, 0};
    for (int c = c0; c < c1; ++c) {
        int4 v = *(const int4*)(counts + (size_t)c * CSR_NBPAD + tl * 4);
        s4.x += v.x; s4.y += v.y; s4.z += v.z; s4.w += v.w;
    }
    *(int4*)((g ? tot2 : tot) + tl * 4) = s4;
    __syncthreads();
    tot[t] += tot2[t];
    tot[t + 256] += tot2[t + 256];
    __syncthreads();
    int pairSum = tot[2 * t] + tot[2 * t + 1];
    sh[t] = pairSum;
    __syncthreads();
    for (int off = 1; off < 256; off <<= 1) {
        int add = (t >= off) ? sh[t - off] : 0;
        __syncthreads();
        sh[t] += add;
        __syncthreads();
    }
    int excl = sh[t] - pairSum;
    bs[2 * t] = excl;
    bs[2 * t + 1] = excl + tot[2 * t];
    __syncthreads();
    for (int b = t; b <= NB; b += 256) bucketStart[b] = bs[b];
    for (int b = t; b < CSR_NBPAD; b += 256) gcur[b] = bs[b];
}

__global__ __launch_bounds__(256) void k_bfill(
        const int* __restrict__ ei, const int* __restrict__ counts,
        int* __restrict__ gcur, int* __restrict__ pairs, int nE) {
    __shared__ int cur[CSR_NBPAD];
    int t = threadIdx.x;
    #pragma unroll
    for (int i = 0; i < 2; ++i) {
        int b = t + i * 256;
        int h = counts[blockIdx.x * CSR_NBPAD + b];
        cur[b] = h ? atomicAdd(&gcur[b], h) : 0;
    }
    __syncthreads();
    int e0 = blockIdx.x * CSR_CHUNK;
    int e1 = min(e0 + CSR_CHUNK, nE);
    for (int e = e0 + t; e < e1; e += 256) {
        int s = ei[e];
        int d = ei[nE + e];
        int p = atomicAdd(&cur[d >> CSR_SH], 1);
        pairs[p] = (s << 8) | (d & 255);
    }
}

__global__ __launch_bounds__(256) void k_csr(
        const int* __restrict__ pairs, const int* __restrict__ bucketStart,
        int* __restrict__ deg, int* __restrict__ rowStart,
        int* __restrict__ srcIdx, int n) {
    __shared__ int cnt[256], scn[256], cur[256];
    __shared__ int buf[CSR_BUFCAP];
    int t = threadIdx.x;
    int bkt = blockIdx.x;
    int eBeg = bucketStart[bkt], eEnd = bucketStart[bkt + 1];
    int node0 = bkt << CSR_SH;
    cnt[t] = 0;
    __syncthreads();
    for (int e = eBeg + t; e < eEnd; e += 256)
        atomicAdd(&cnt[pairs[e] & 255], 1);
    __syncthreads();
    int myc = cnt[t];
    scn[t] = myc;
    __syncthreads();
    for (int off = 1; off < 256; off <<= 1) {
        int add = (t >= off) ? scn[t - off] : 0;
        __syncthreads();
        scn[t] += add;
        __syncthreads();
    }
    int excl = scn[t] - myc;
    cur[t] = excl;
    int node = node0 + t;
    if (node < n) { deg[node] = myc; rowStart[node] = eBeg + excl; }
    __syncthreads();
    for (int e = eBeg + t; e < eEnd; e += 256) {
        int pk = pairs[e];
        int p = atomicAdd(&cur[pk & 255], 1);
        int src = pk >> 8;
        if (p < CSR_BUFCAP) buf[p] = src;
        else srcIdx[eBeg + p] = src;   // statistically never at this size
    }
    __syncthreads();
    int m = min(eEnd - eBeg, CSR_BUFCAP);
    for (int i = t; i < m; i += 256) srcIdx[eBeg + i] = buf[i];
}

// ---- layer-1 gather (bf16): 16 lanes/node, lane owns 8 ch; 4-edge unroll.
__global__ __launch_bounds__(256) void k_gather1(
        const unsigned short* __restrict__ xb, const int* __restrict__ rowStart,
        const int* __restrict__ deg, const int* __restrict__ srcIdx,
        unsigned short* __restrict__ aggb, int n) {
    int t = threadIdx.x;
    int q = t & 15, grp = t >> 4;
    int node = blockIdx.x * 16 + grp;
    if (node >= n) return;
    int beg = rowStart[node];
    int d = deg[node];
    int end = beg + d;
    float a0[8] = {}, a1[8] = {}, a2[8] = {}, a3[8] = {};
    int e = beg;
    for (; e + 4 <= end; e += 4) {
        int s0 = srcIdx[e], s1v = srcIdx[e + 1], s2 = srcIdx[e + 2], s3 = srcIdx[e + 3];
        s8v v0 = *(const s8v*)(xb + (size_t)s0 * 128 + q * 8);
        s8v v1 = *(const s8v*)(xb + (size_t)s1v * 128 + q * 8);
        s8v v2 = *(const s8v*)(xb + (size_t)s2 * 128 + q * 8);
        s8v v3 = *(const s8v*)(xb + (size_t)s3 * 128 + q * 8);
        #pragma unroll
        for (int u = 0; u < 8; ++u) {
            a0[u] += bf2f((unsigned short)v0[u]);
            a1[u] += bf2f((unsigned short)v1[u]);
            a2[u] += bf2f((unsigned short)v2[u]);
            a3[u] += bf2f((unsigned short)v3[u]);
        }
    }
    for (; e < end; ++e) {
        s8v v0 = *(const s8v*)(xb + (size_t)srcIdx[e] * 128 + q * 8);
        #pragma unroll
        for (int u = 0; u < 8; ++u) a0[u] += bf2f((unsigned short)v0[u]);
    }
    float ic = 1.0f / fmaxf((float)d, 1.0f);
    union { s8v v; unsigned short u[8]; } o;
    #pragma unroll
    for (int u = 0; u < 8; ++u)
        o.u[u] = f2bf((a0[u] + a1[u] + a2[u] + a3[u]) * ic);
    *(s8v*)(aggb + (size_t)node * 128 + q * 8) = o.v;
}

// Async 16B global->LDS (gfx950). Dest is wave-uniform base + lane*16;
// our LDS layout is lane-linear so per-lane dest == HW dest.
#define GLL16(GSRC, LDST) \
    __builtin_amdgcn_global_load_lds( \
        (__attribute__((address_space(1))) void*)(void*)(GSRC), \
        (__attribute__((address_space(3))) void*)(LDST), 16, 0, 0)

// ---- GEMM1 (bf16 MFMA): block 128x128, K=256 (aggb then xb), BK=64.
// Per round: stage two 32-col subtiles (each byte-identical to R15's proven
// 0-conflict layout: stride-32 linear, slot XOR p^((row>>1)&3) both sides),
// one __syncthreads pair, 32 MFMAs/wave. 4 rounds total.
__global__ __launch_bounds__(256, 3) void k_gemm1(
        const unsigned short* __restrict__ xb, const unsigned short* __restrict__ aggb,
        const unsigned short* __restrict__ wB1, const float* __restrict__ b1l,
        unsigned short* __restrict__ s1b, float* __restrict__ stats, int n) {
    __shared__ __align__(16) unsigned short xs[2][128 * 32];  // 2 subtiles x 8KB
    __shared__ __align__(16) unsigned short ws[2][128 * 32];
    int t = threadIdx.x;
    int w = t >> 6, L = t & 63;
    int q = L >> 4, lm = L & 15;
    int wr0 = (w >> 1) * 64;     // wave row base
    int wc0 = (w & 1) * 64;      // wave col base
    int r0 = blockIdx.x * 128;

    fx4 acc[4][4];
    fx4 z4 = {0.f, 0.f, 0.f, 0.f};
    #pragma unroll
    for (int r = 0; r < 4; ++r)
        #pragma unroll
        for (int c = 0; c < 4; ++c) acc[r][c] = z4;

    for (int kt = 0; kt < 4; ++kt) {
        __syncthreads();   // previous round's reads done -> buffers reusable
        #pragma unroll
        for (int s = 0; s < 2; ++s) {
            int kt2 = kt * 2 + s;                       // 0..7
            const unsigned short* src = (kt2 < 4) ? aggb : xb;
            int kbase = (kt2 & 3) * 32;
            #pragma unroll
            for (int it = 0; it < 2; ++it) {
                int i = t + it * 256;                    // 0..511
                int row = i >> 2, p = i & 3;
                int sl = p ^ ((row >> 1) & 3);           // R15 slot swizzle
                int gr = r0 + row; gr = gr < n ? gr : (n - 1);
                GLL16(src + (size_t)gr * 128 + kbase + sl * 8, &xs[s][i * 8]);
                GLL16(wB1 + (size_t)row * 256 + kt2 * 32 + sl * 8, &ws[s][i * 8]);
            }
        }
        __syncthreads();   // full vmcnt(0) drain before s_barrier -> DMA landed
        #pragma unroll
        for (int s = 0; s < 2; ++s) {
            s8v af[4], bfr[4];
            #pragma unroll
            for (int r = 0; r < 4; ++r) {
                int row = wr0 + r * 16 + lm;
                af[r] = *(const s8v*)&xs[s][row * 32 + ((q ^ ((row >> 1) & 3)) << 3)];
            }
            #pragma unroll
            for (int c = 0; c < 4; ++c) {
                int row = wc0 + c * 16 + lm;
                bfr[c] = *(const s8v*)&ws[s][row * 32 + ((q ^ ((row >> 1) & 3)) << 3)];
            }
            #pragma unroll
            for (int r = 0; r < 4; ++r)
                #pragma unroll
                for (int c = 0; c < 4; ++c)
                    acc[r][c] = __builtin_amdgcn_mfma_f32_16x16x32_bf16(af[r], bfr[c], acc[r][c], 0, 0, 0);
        }
    }

    // ---- epilogue: bias -> row L2-norm -> scale -> bf16 store -> BN stats
    float bj[4];
    #pragma unroll
    for (int c = 0; c < 4; ++c) bj[c] = b1l[wc0 + c * 16 + lm];
    #pragma unroll
    for (int r = 0; r < 4; ++r)
        #pragma unroll
        for (int c = 0; c < 4; ++c) acc[r][c] += bj[c];

    fx4 pr[4];
    #pragma unroll
    for (int r = 0; r < 4; ++r) {
        fx4 p = acc[r][0] * acc[r][0];
        #pragma unroll
        for (int c = 1; c < 4; ++c) p += acc[r][c] * acc[r][c];
        #pragma unroll
        for (int off = 1; off <= 8; off <<= 1)
            #pragma unroll
            for (int i2 = 0; i2 < 4; ++i2) p[i2] += __shfl_xor(p[i2], off, 64);
        pr[r] = p;
    }

    __syncthreads();   // xs/ws free -> overlay reductions
    float* norm2 = (float*)xs;          // [128][2]
    float* invn  = (float*)xs + 256;    // [128]
    float* statS = (float*)ws;          // [128][2]
    float* statQ = (float*)ws + 256;    // [128][2]
    if (lm == 0) {
        #pragma unroll
        for (int r = 0; r < 4; ++r)
            #pragma unroll
            for (int i = 0; i < 4; ++i)
                norm2[(wr0 + r * 16 + q * 4 + i) * 2 + (w & 1)] = pr[r][i];
    }
    __syncthreads();
    if (t < 128) {
        float s = norm2[t * 2] + norm2[t * 2 + 1];
        invn[t] = 1.0f / fmaxf(sqrtf(s), 1e-12f);
    }
    __syncthreads();

    float cS[4] = {}, cQ[4] = {};
    #pragma unroll
    for (int r = 0; r < 4; ++r) {
        int rowb = wr0 + r * 16 + q * 4;
        fx4 iv = *(const fx4*)&invn[rowb];
        #pragma unroll
        for (int c = 0; c < 4; ++c) {
            fx4 v = acc[r][c] * iv;
            int col = wc0 + c * 16 + lm;
            #pragma unroll
            for (int i = 0; i < 4; ++i) {
                int gr = r0 + rowb + i;
                if (gr < n) {
                    s1b[(size_t)gr * 128 + col] = f2bf(v[i]);
                    cS[c] += v[i];
                    cQ[c] += v[i] * v[i];
                }
            }
        }
    }
    #pragma unroll
    for (int off = 16; off <= 32; off <<= 1)
        #pragma unroll
        for (int c = 0; c < 4; ++c) {
            cS[c] += __shfl_xor(cS[c], off, 64);
            cQ[c] += __shfl_xor(cQ[c], off, 64);
        }
    if (q == 0) {
        #pragma unroll
        for (int c = 0; c < 4; ++c) {
            int col = wc0 + c * 16 + lm;
            statS[col * 2 + (w >> 1)] = cS[c];
            statQ[col * 2 + (w >> 1)] = cQ[c];
        }
    }
    __syncthreads();
    if (t < 128) {
        atomicAdd(&stats[t],       statS[t * 2] + statS[t * 2 + 1]);
        atomicAdd(&stats[128 + t], statQ[t * 2] + statQ[t * 2 + 1]);
    }
}

// ---- GEMM2 (bf16 MFMA) with inline BN finalize, BK=64 (2 rounds).
// BN+ReLU applied at the A-fragment after ds_read (identical arithmetic).
__global__ __launch_bounds__(256, 3) void k_gemm2(
        const unsigned short* __restrict__ s1b, const unsigned short* __restrict__ wB2p,
        const float* __restrict__ stats, const float* __restrict__ gamma,
        const float* __restrict__ beta, const float* __restrict__ b2l,
        unsigned short* __restrict__ y2b, float* __restrict__ rbuf, int n) {
    __shared__ __align__(16) unsigned short xs[2][128 * 32];
    __shared__ __align__(16) unsigned short ws[2][128 * 32];
    __shared__ __align__(16) float abuf[128];
    __shared__ __align__(16) float bbuf[128];
    int t = threadIdx.x;
    int w = t >> 6, L = t & 63;
    int q = L >> 4, lm = L & 15;
    int wr0 = (w >> 1) * 64, wc0 = (w & 1) * 64;
    int r0 = blockIdx.x * 128;

    if (t < 128) {
        float s = stats[t], qv = stats[128 + t];
        float fn = (float)n;
        float mean = s / fn;
        float var = qv / fn - mean * mean;   // biased variance
        float istd = rsqrtf(var + 1e-5f);
        float a = gamma[t] * istd;
        abuf[t] = a;
        bbuf[t] = beta[t] - mean * a;
    }
    __syncthreads();   // abuf/bbuf visible to all

    fx4 acc[4][4];
    fx4 z4 = {0.f, 0.f, 0.f, 0.f};
    #pragma unroll
    for (int r = 0; r < 4; ++r)
        #pragma unroll
        for (int c = 0; c < 4; ++c) acc[r][c] = z4;

    for (int kt = 0; kt < 2; ++kt) {
        __syncthreads();
        #pragma unroll
        for (int s = 0; s < 2; ++s) {
            int kt2 = kt * 2 + s;                       // 0..3
            int kbase = kt2 * 32;
            #pragma unroll
            for (int it = 0; it < 2; ++it) {
                int i = t + it * 256;
                int row = i >> 2, p = i & 3;
                int sl = p ^ ((row >> 1) & 3);
                int gr = r0 + row; gr = gr < n ? gr : (n - 1);
                GLL16(s1b + (size_t)gr * 128 + kbase + sl * 8, &xs[s][i * 8]);
                GLL16(wB2p + (size_t)row * 128 + kbase + sl * 8, &ws[s][i * 8]);
            }
        }
        __syncthreads();   // DMA drained -> tiles visible
        #pragma unroll
        for (int s = 0; s < 2; ++s) {
            int kb = (kt * 2 + s) * 32 + q * 8;
            fx4 a0 = *(const fx4*)&abuf[kb];
            fx4 a1 = *(const fx4*)&abuf[kb + 4];
            fx4 b0 = *(const fx4*)&bbuf[kb];
            fx4 b1 = *(const fx4*)&bbuf[kb + 4];
            s8v af[4], bfr[4];
            #pragma unroll
            for (int r = 0; r < 4; ++r) {
                int row = wr0 + r * 16 + lm;
                s8v sv = *(const s8v*)&xs[s][row * 32 + ((q ^ ((row >> 1) & 3)) << 3)];
                union { s8v v; unsigned short u[8]; } o;
                #pragma unroll
                for (int u = 0; u < 4; ++u) {
                    float h0 = fmaxf(fmaf(a0[u], bf2f((unsigned short)sv[u]), b0[u]), 0.f);
                    float h1 = fmaxf(fmaf(a1[u], bf2f((unsigned short)sv[u + 4]), b1[u]), 0.f);
                    o.u[u]     = f2bf(h0);
                    o.u[u + 4] = f2bf(h1);
                }
                af[r] = o.v;
            }
            #pragma unroll
            for (int c = 0; c < 4; ++c) {
                int row = wc0 + c * 16 + lm;
                bfr[c] = *(const s8v*)&ws[s][row * 32 + ((q ^ ((row >> 1) & 3)) << 3)];
            }
            #pragma unroll
            for (int r = 0; r < 4; ++r)
                #pragma unroll
                for (int c = 0; c < 4; ++c)
                    acc[r][c] = __builtin_amdgcn_mfma_f32_16x16x32_bf16(af[r], bfr[c], acc[r][c], 0, 0, 0);
        }
    }

    // epilogue: y2b bf16 stride 64 (j<47) / rbuf fp32 stride 48 + b2l (j 47..93)
    #pragma unroll
    for (int c = 0; c < 4; ++c) {
        int col = wc0 + c * 16 + lm;
        float bb = (col >= 47 && col < 94) ? b2l[col - 47] : 0.f;
        #pragma unroll
        for (int r = 0; r < 4; ++r) {
            int rowb = wr0 + r * 16 + q * 4;
            #pragma unroll
            for (int i = 0; i < 4; ++i) {
                int gr = r0 + rowb + i;
                if (gr >= n) continue;
                float v = acc[r][c][i];
                if (col < 47)      y2b[(size_t)gr * 64 + col] = f2bf(v);
                else if (col < 94) rbuf[(size_t)gr * 48 + (col - 47)] = v + bb;
            }
        }
    }
}

// ---- layer-2 gather + combine + L2-norm. 16 lanes/node (lane owns 4 ch),
// 16 nodes/block, 8-edge unroll -> 4 independent load chains per wave.
__global__ __launch_bounds__(256) void k_gather2_final(
        const unsigned short* __restrict__ y2b, const float* __restrict__ rbuf,
        const int* __restrict__ rowStart, const int* __restrict__ deg,
        const int* __restrict__ srcIdx, float* __restrict__ out, int n) {
    int t = threadIdx.x;
    int q = t & 15, grp = t >> 4;
    int node = blockIdx.x * 16 + grp;
    if (node >= n) return;
    int beg = rowStart[node];
    int d = deg[node];
    int end = beg + d;
    float acc[4] = {0.f, 0.f, 0.f, 0.f};
    int e = beg;
    for (; e + 8 <= end; e += 8) {
        int s0 = srcIdx[e],     s1v = srcIdx[e + 1];
        int s2 = srcIdx[e + 2], s3  = srcIdx[e + 3];
        int s4 = srcIdx[e + 4], s5  = srcIdx[e + 5];
        int s6 = srcIdx[e + 6], s7  = srcIdx[e + 7];
        s4v v0 = *(const s4v*)(y2b + (size_t)s0 * 64 + q * 4);
        s4v v1 = *(const s4v*)(y2b + (size_t)s1v * 64 + q * 4);
        s4v v2 = *(const s4v*)(y2b + (size_t)s2 * 64 + q * 4);
        s4v v3 = *(const s4v*)(y2b + (size_t)s3 * 64 + q * 4);
        s4v v4 = *(const s4v*)(y2b + (size_t)s4 * 64 + q * 4);
        s4v v5 = *(const s4v*)(y2b + (size_t)s5 * 64 + q * 4);
        s4v v6 = *(const s4v*)(y2b + (size_t)s6 * 64 + q * 4);
        s4v v7 = *(const s4v*)(y2b + (size_t)s7 * 64 + q * 4);
        #pragma unroll
        for (int u = 0; u < 4; ++u) {
            acc[u] += (bf2f((unsigned short)v0[u]) + bf2f((unsigned short)v1[u]))
                    + (bf2f((unsigned short)v2[u]) + bf2f((unsigned short)v3[u]))
                    + (bf2f((unsigned short)v4[u]) + bf2f((unsigned short)v5[u]))
                    + (bf2f((unsigned short)v6[u]) + bf2f((unsigned short)v7[u]));
        }
    }
    for (; e + 4 <= end; e += 4) {
        int s0 = srcIdx[e],     s1v = srcIdx[e + 1];
        int s2 = srcIdx[e + 2], s3  = srcIdx[e + 3];
        s4v v0 = *(const s4v*)(y2b + (size_t)s0 * 64 + q * 4);
        s4v v1 = *(const s4v*)(y2b + (size_t)s1v * 64 + q * 4);
        s4v v2 = *(const s4v*)(y2b + (size_t)s2 * 64 + q * 4);
        s4v v3 = *(const s4v*)(y2b + (size_t)s3 * 64 + q * 4);
        #pragma unroll
        for (int u = 0; u < 4; ++u)
            acc[u] += (bf2f((unsigned short)v0[u]) + bf2f((unsigned short)v1[u]))
                    + (bf2f((unsigned short)v2[u]) + bf2f((unsigned short)v3[u]));
    }
    for (; e < end; ++e) {
        s4v v0 = *(const s4v*)(y2b + (size_t)srcIdx[e] * 64 + q * 4);
        #pragma unroll
        for (int u = 0; u < 4; ++u) acc[u] += bf2f((unsigned short)v0[u]);
    }
    float ic = 1.0f / fmaxf((float)d, 1.0f);
    fx4 rb = *(const fx4*)(rbuf + (size_t)node * 48 + q * 4);
    float vi[4];
    float ss = 0.f;
    #pragma unroll
    for (int u = 0; u < 4; ++u) {
        int ch = q * 4 + u;
        float v = (ch < 47) ? (acc[u] * ic + rb[u]) : 0.f;   // select masks pad (NaN-safe)
        vi[u] = v;
        ss += v * v;
    }
    #pragma unroll
    for (int off = 1; off <= 8; off <<= 1) ss += __shfl_xor(ss, off, 64);
    float inv = 1.0f / fmaxf(sqrtf(ss), 1e-12f);
    #pragma unroll
    for (int u = 0; u < 4; ++u) {
        int ch = q * 4 + u;
        if (ch < 47) out[(size_t)node * 47 + ch] = vi[u] * inv;
    }
}

extern "C" void kernel_launch(void* const* d_in, const int* in_sizes, int n_in,
                              void* d_out, int out_size, void* d_ws, size_t ws_size,
                              hipStream_t stream) {
    const float* x     = (const float*)d_in[0];
    const int*   ei    = (const int*)d_in[1];
    const float* w1l   = (const float*)d_in[2];
    const float* b1l   = (const float*)d_in[3];
    const float* w1r   = (const float*)d_in[4];
    const float* gamma = (const float*)d_in[5];
    const float* beta  = (const float*)d_in[6];
    const float* w2l   = (const float*)d_in[7];
    const float* b2l   = (const float*)d_in[8];
    const float* w2r   = (const float*)d_in[9];
    float* out = (float*)d_out;

    int n  = in_sizes[0] / 128;   // 100000
    int nE = in_sizes[1] / 2;     // 800000

    int NB  = (n + 255) >> 8;                    // 391 buckets
    int nCh = (nE + CSR_CHUNK - 1) / CSR_CHUNK;  // 98 chunks

    // ---- workspace layout ----
    // deg[n](int) | stats[256](f32) | rowStart[n] | meta[n] | srcIdx[nE]
    // | xb[128n bf16] | aggb[128n bf16] | s1b[128n bf16] | wB1 | wB2p
    // meta: counts[nCh*512] then bucketStart at +60000, gcur[512] at +61000.
    // pairs[nE] overlays s1b (dead until gemm1).
    // y2b[64n bf16, 1 line/row] + rbuf[48n f32] overlay xb+aggb.
    int* deg       = (int*)d_ws;
    float* stats   = (float*)(deg + n);
    int* rowStart  = (int*)(stats + 256);
    int* meta      = rowStart + n;
    int* srcIdx    = meta + n;
    unsigned short* xb   = (unsigned short*)(srcIdx + nE);
    unsigned short* aggb = xb + (size_t)n * 128;
    unsigned short* s1b  = aggb + (size_t)n * 128;
    unsigned short* wB1  = s1b + (size_t)n * 128;
    unsigned short* wB2p = wB1 + 32768;
    int* counts      = meta;
    int* bucketStart = meta + 60000;
    int* gcur        = meta + 61000;
    int* pairs       = (int*)s1b;             // packed (src<<8)|(dst&255)
    unsigned short* y2b = xb;                 // stride 64 shorts (128B/row)
    float* rbuf = (float*)(y2b + (size_t)n * 64);   // stride 48 f32

    int prepTotal  = n * 16 + 32768 + 16384 + 256;
    int prepBlocks = (prepTotal + 255) / 256;

    // 1: prep (xcast | weight casts | stats zero | bcount histograms)
    k_prep<<<prepBlocks + nCh, 256, 0, stream>>>(
        x, w1l, w1r, w2l, w2r, ei, xb, wB1, wB2p, stats, counts, n, nE, prepBlocks);
    // 2-4: CSR build (bucketed counting sort, runtime range reservation)
    k_bmeta<<<1, 256, 0, stream>>>(counts, bucketStart, gcur, nCh, NB);
    k_bfill<<<nCh, 256, 0, stream>>>(ei, counts, gcur, pairs, nE);
    k_csr<<<NB, 256, 0, stream>>>(pairs, bucketStart, deg, rowStart, srcIdx, n);
    // 5-6: layer 1
    k_gather1<<<(n + 15) / 16, 256, 0, stream>>>(xb, rowStart, deg, srcIdx, aggb, n);
    k_gemm1<<<(n + 127) / 128, 256, 0, stream>>>(xb, aggb, wB1, b1l, s1b, stats, n);
    // 7-8: layer 2 (BN finalize inlined in gemm2)
    k_gemm2<<<(n + 127) / 128, 256, 0, stream>>>(
        s1b, wB2p, stats, gamma, beta, b2l, y2b, rbuf, n);
    k_gather2_final<<<(n + 15) / 16, 256, 0, stream>>>(y2b, rbuf, rowStart, deg, srcIdx, out, n);
}

// Round 9
// 261.756 us; speedup vs baseline: 1.1411x; 1.0894x over previous
//
#include <hip/hip_runtime.h>
#include <cstdint>

// GNN: 2-layer GraphSAGE (mean aggr, L2-normalize) + BatchNorm(train) + ReLU.
// N=100000 nodes, E=800000 edges, C: 128 -> 128 -> 47.
//
// Round 19: gemm1 stuck at ~40-43us across 5 structures. Root cause finally
// isolated: grid 782 blocks = 3 blocks/CU = ONE serial block-wave; all
// resident blocks phase-lock (stage/drain/compute in lockstep) so HBM runs
// at 1.2 TB/s with memory idle during compute phases. Fix: HALVE the M-tile
// to 64 rows -> grid 1563, launch_bounds(256,4), 4+ blocks/CU, 2 dispatch
// generations -> decorrelated phases. Staging keeps R15's byte-identical
// 0-conflict subtile layout (stride-32 linear, slot XOR p^((row>>1)&3) both
// sides) and plain __syncthreads discipline. gemm1 stats atomics (now 2x
// blocks) split 8 ways by blockIdx&7, summed in gemm2's BN-coeff read.
// Rest unchanged from R15/R18 lineage (285us).

typedef __attribute__((ext_vector_type(8))) short s8v;
typedef __attribute__((ext_vector_type(4))) short s4v;
typedef __attribute__((ext_vector_type(4))) float fx4;

#define CSR_CHUNK 8192
#define CSR_SH 8            // 256 nodes per bucket
#define CSR_NBPAD 512       // padded bucket count (NB = ceil(n/256) = 391)
#define CSR_BUFCAP 3072     // LDS srcbuf cap per bucket (mean 2046, +20 sigma)

static __device__ __forceinline__ float bf2f(unsigned short h) {
    union { unsigned int u; float f; } c; c.u = (unsigned int)h << 16; return c.f;
}
static __device__ __forceinline__ unsigned short f2bf(float f) {
    union { float f; unsigned int u; } c; c.f = f;
    unsigned int u = c.u;
    return (unsigned short)((u + 0x7FFF + ((u >> 16) & 1)) >> 16);   // RNE
}

// ---- merged prep: x->bf16 | weight casts | stats zero | bcount histograms.
__global__ __launch_bounds__(256) void k_prep(
        const float* __restrict__ x, const float* __restrict__ w1l,
        const float* __restrict__ w1r, const float* __restrict__ w2l,
        const float* __restrict__ w2r, const int* __restrict__ ei,
        unsigned short* __restrict__ xb, unsigned short* __restrict__ wB1,
        unsigned short* __restrict__ wB2p, float* __restrict__ stats,
        int* __restrict__ counts, int n, int nE, int prepBlocks) {
    __shared__ int hist[CSR_NBPAD];
    int t = threadIdx.x;
    if ((int)blockIdx.x >= prepBlocks) {
        int chunk = blockIdx.x - prepBlocks;
        hist[t] = 0; hist[t + 256] = 0;
        __syncthreads();
        int e0 = chunk * CSR_CHUNK;
        int e1 = min(e0 + CSR_CHUNK, nE);
        for (int e = e0 + t; e < e1; e += 256)
            atomicAdd(&hist[ei[nE + e] >> CSR_SH], 1);
        __syncthreads();
        counts[chunk * CSR_NBPAD + t] = hist[t];
        counts[chunk * CSR_NBPAD + t + 256] = hist[t + 256];
        return;
    }
    int idx = blockIdx.x * 256 + t;
    int nx = n * 16;
    if (idx < nx) {
        float4 a = ((const float4*)x)[idx * 2];
        float4 b = ((const float4*)x)[idx * 2 + 1];
        union { s8v v; unsigned short u[8]; } o;
        o.u[0] = f2bf(a.x); o.u[1] = f2bf(a.y); o.u[2] = f2bf(a.z); o.u[3] = f2bf(a.w);
        o.u[4] = f2bf(b.x); o.u[5] = f2bf(b.y); o.u[6] = f2bf(b.z); o.u[7] = f2bf(b.w);
        ((s8v*)xb)[idx] = o.v;
        return;
    }
    idx -= nx;
    if (idx < 32768) {
        int j = idx >> 8, k = idx & 255;
        float v = (k < 128) ? w1l[j * 128 + k] : w1r[j * 128 + (k - 128)];
        wB1[idx] = f2bf(v);
        return;
    }
    idx -= 32768;
    if (idx < 16384) {
        int j = idx >> 7, k = idx & 127;
        float v = 0.f;
        if (j < 47)      v = w2l[j * 128 + k];
        else if (j < 94) v = w2r[(j - 47) * 128 + k];
        wB2p[idx] = f2bf(v);
        return;
    }
    idx -= 16384;
    if (idx < 2048) stats[idx] = 0.f;   // 8-way split stats copies
}

// ---- CSR build: bucketed counting sort -------------------------------
__global__ __launch_bounds__(256) void k_bmeta(
        const int* __restrict__ counts, int* __restrict__ bucketStart,
        int* __restrict__ gcur, int nCh, int NB) {
    __shared__ int tot[CSR_NBPAD], tot2[CSR_NBPAD], sh[256], bs[CSR_NBPAD];
    int t = threadIdx.x;
    int tl = t & 127, g = t >> 7;
    int half = (nCh + 1) >> 1;
    int c0 = g * half, c1 = min(nCh, c0 + half);
    int4 s4 = {0, 0, 0, 0};
    for (int c = c0; c < c1; ++c) {
        int4 v = *(const int4*)(counts + (size_t)c * CSR_NBPAD + tl * 4);
        s4.x += v.x; s4.y += v.y; s4.z += v.z; s4.w += v.w;
    }
    *(int4*)((g ? tot2 : tot) + tl * 4) = s4;
    __syncthreads();
    tot[t] += tot2[t];
    tot[t + 256] += tot2[t + 256];
    __syncthreads();
    int pairSum = tot[2 * t] + tot[2 * t + 1];
    sh[t] = pairSum;
    __syncthreads();
    for (int off = 1; off < 256; off <<= 1) {
        int add = (t >= off) ? sh[t - off] : 0;
        __syncthreads();
        sh[t] += add;
        __syncthreads();
    }
    int excl = sh[t] - pairSum;
    bs[2 * t] = excl;
    bs[2 * t + 1] = excl + tot[2 * t];
    __syncthreads();
    for (int b = t; b <= NB; b += 256) bucketStart[b] = bs[b];
    for (int b = t; b < CSR_NBPAD; b += 256) gcur[b] = bs[b];
}

__global__ __launch_bounds__(256) void k_bfill(
        const int* __restrict__ ei, const int* __restrict__ counts,
        int* __restrict__ gcur, int* __restrict__ pairs, int nE) {
    __shared__ int cur[CSR_NBPAD];
    int t = threadIdx.x;
    #pragma unroll
    for (int i = 0; i < 2; ++i) {
        int b = t + i * 256;
        int h = counts[blockIdx.x * CSR_NBPAD + b];
        cur[b] = h ? atomicAdd(&gcur[b], h) : 0;
    }
    __syncthreads();
    int e0 = blockIdx.x * CSR_CHUNK;
    int e1 = min(e0 + CSR_CHUNK, nE);
    for (int e = e0 + t; e < e1; e += 256) {
        int s = ei[e];
        int d = ei[nE + e];
        int p = atomicAdd(&cur[d >> CSR_SH], 1);
        pairs[p] = (s << 8) | (d & 255);
    }
}

__global__ __launch_bounds__(256) void k_csr(
        const int* __restrict__ pairs, const int* __restrict__ bucketStart,
        int* __restrict__ deg, int* __restrict__ rowStart,
        int* __restrict__ srcIdx, int n) {
    __shared__ int cnt[256], scn[256], cur[256];
    __shared__ int buf[CSR_BUFCAP];
    int t = threadIdx.x;
    int bkt = blockIdx.x;
    int eBeg = bucketStart[bkt], eEnd = bucketStart[bkt + 1];
    int node0 = bkt << CSR_SH;
    cnt[t] = 0;
    __syncthreads();
    for (int e = eBeg + t; e < eEnd; e += 256)
        atomicAdd(&cnt[pairs[e] & 255], 1);
    __syncthreads();
    int myc = cnt[t];
    scn[t] = myc;
    __syncthreads();
    for (int off = 1; off < 256; off <<= 1) {
        int add = (t >= off) ? scn[t - off] : 0;
        __syncthreads();
        scn[t] += add;
        __syncthreads();
    }
    int excl = scn[t] - myc;
    cur[t] = excl;
    int node = node0 + t;
    if (node < n) { deg[node] = myc; rowStart[node] = eBeg + excl; }
    __syncthreads();
    for (int e = eBeg + t; e < eEnd; e += 256) {
        int pk = pairs[e];
        int p = atomicAdd(&cur[pk & 255], 1);
        int src = pk >> 8;
        if (p < CSR_BUFCAP) buf[p] = src;
        else srcIdx[eBeg + p] = src;   // statistically never at this size
    }
    __syncthreads();
    int m = min(eEnd - eBeg, CSR_BUFCAP);
    for (int i = t; i < m; i += 256) srcIdx[eBeg + i] = buf[i];
}

// ---- layer-1 gather (bf16): 16 lanes/node, lane owns 8 ch; 4-edge unroll.
__global__ __launch_bounds__(256) void k_gather1(
        const unsigned short* __restrict__ xb, const int* __restrict__ rowStart,
        const int* __restrict__ deg, const int* __restrict__ srcIdx,
        unsigned short* __restrict__ aggb, int n) {
    int t = threadIdx.x;
    int q = t & 15, grp = t >> 4;
    int node = blockIdx.x * 16 + grp;
    if (node >= n) return;
    int beg = rowStart[node];
    int d = deg[node];
    int end = beg + d;
    float a0[8] = {}, a1[8] = {}, a2[8] = {}, a3[8] = {};
    int e = beg;
    for (; e + 4 <= end; e += 4) {
        int s0 = srcIdx[e], s1v = srcIdx[e + 1], s2 = srcIdx[e + 2], s3 = srcIdx[e + 3];
        s8v v0 = *(const s8v*)(xb + (size_t)s0 * 128 + q * 8);
        s8v v1 = *(const s8v*)(xb + (size_t)s1v * 128 + q * 8);
        s8v v2 = *(const s8v*)(xb + (size_t)s2 * 128 + q * 8);
        s8v v3 = *(const s8v*)(xb + (size_t)s3 * 128 + q * 8);
        #pragma unroll
        for (int u = 0; u < 8; ++u) {
            a0[u] += bf2f((unsigned short)v0[u]);
            a1[u] += bf2f((unsigned short)v1[u]);
            a2[u] += bf2f((unsigned short)v2[u]);
            a3[u] += bf2f((unsigned short)v3[u]);
        }
    }
    for (; e < end; ++e) {
        s8v v0 = *(const s8v*)(xb + (size_t)srcIdx[e] * 128 + q * 8);
        #pragma unroll
        for (int u = 0; u < 8; ++u) a0[u] += bf2f((unsigned short)v0[u]);
    }
    float ic = 1.0f / fmaxf((float)d, 1.0f);
    union { s8v v; unsigned short u[8]; } o;
    #pragma unroll
    for (int u = 0; u < 8; ++u)
        o.u[u] = f2bf((a0[u] + a1[u] + a2[u] + a3[u]) * ic);
    *(s8v*)(aggb + (size_t)node * 128 + q * 8) = o.v;
}

// Async 16B global->LDS (gfx950). Dest is wave-uniform base + lane*16;
// our LDS layout is lane-linear so per-lane dest == HW dest.
#define GLL16(GSRC, LDST) \
    __builtin_amdgcn_global_load_lds( \
        (__attribute__((address_space(1))) void*)(void*)(GSRC), \
        (__attribute__((address_space(3))) void*)(LDST), 16, 0, 0)

// ---- GEMM1 (bf16 MFMA): block 64x128, K=256 (aggb then xb), BK=32,
// 8 rounds. Grid 1563 -> 4+ blocks/CU (phase decorrelation). R15's proven
// 0-conflict subtile layout and __syncthreads discipline.
__global__ __launch_bounds__(256, 4) void k_gemm1(
        const unsigned short* __restrict__ xb, const unsigned short* __restrict__ aggb,
        const unsigned short* __restrict__ wB1, const float* __restrict__ b1l,
        unsigned short* __restrict__ s1b, float* __restrict__ stats, int n) {
    __shared__ __align__(16) unsigned short xs[64 * 32];    // 4KB [row][32]
    __shared__ __align__(16) unsigned short ws[128 * 32];   // 8KB [j][32]
    __shared__ float norm2[128];   // [64][2]
    __shared__ float invn[64];
    __shared__ float statS[256];   // [128][2]
    __shared__ float statQ[256];   // [128][2]
    int t = threadIdx.x;
    int w = t >> 6, L = t & 63;
    int q = L >> 4, lm = L & 15;
    int wr0 = (w >> 1) * 32;     // wave row base (0 or 32)
    int wc0 = (w & 1) * 64;      // wave col base (0 or 64)
    int r0 = blockIdx.x * 64;

    fx4 acc[2][4];
    fx4 z4 = {0.f, 0.f, 0.f, 0.f};
    #pragma unroll
    for (int r = 0; r < 2; ++r)
        #pragma unroll
        for (int c = 0; c < 4; ++c) acc[r][c] = z4;

    for (int kt = 0; kt < 8; ++kt) {
        const unsigned short* src = (kt < 4) ? aggb : xb;
        int kbase = (kt & 3) * 32;
        __syncthreads();   // previous round's reads done -> buffers reusable
        {
            // xs: 256 x 16B chunks (1/thread)
            int row = t >> 2, p = t & 3;
            int sl = p ^ ((row >> 1) & 3);
            int gr = r0 + row; gr = gr < n ? gr : (n - 1);
            GLL16(src + (size_t)gr * 128 + kbase + sl * 8, &xs[t * 8]);
            // ws: 512 x 16B chunks (2/thread)
            #pragma unroll
            for (int it = 0; it < 2; ++it) {
                int i = t + it * 256;
                int wrow = i >> 2, wp = i & 3;
                int wsl = wp ^ ((wrow >> 1) & 3);
                GLL16(wB1 + (size_t)wrow * 256 + kt * 32 + wsl * 8, &ws[i * 8]);
            }
        }
        __syncthreads();   // full vmcnt(0) drain before s_barrier -> DMA landed
        s8v af[2], bfr[4];
        #pragma unroll
        for (int r = 0; r < 2; ++r) {
            int row = wr0 + r * 16 + lm;
            af[r] = *(const s8v*)&xs[row * 32 + ((q ^ ((row >> 1) & 3)) << 3)];
        }
        #pragma unroll
        for (int c = 0; c < 4; ++c) {
            int row = wc0 + c * 16 + lm;
            bfr[c] = *(const s8v*)&ws[row * 32 + ((q ^ ((row >> 1) & 3)) << 3)];
        }
        #pragma unroll
        for (int r = 0; r < 2; ++r)
            #pragma unroll
            for (int c = 0; c < 4; ++c)
                acc[r][c] = __builtin_amdgcn_mfma_f32_16x16x32_bf16(af[r], bfr[c], acc[r][c], 0, 0, 0);
    }

    // ---- epilogue: bias -> row L2-norm -> scale -> bf16 store -> BN stats
    float bj[4];
    #pragma unroll
    for (int c = 0; c < 4; ++c) bj[c] = b1l[wc0 + c * 16 + lm];
    #pragma unroll
    for (int r = 0; r < 2; ++r)
        #pragma unroll
        for (int c = 0; c < 4; ++c) acc[r][c] += bj[c];

    fx4 pr[2];
    #pragma unroll
    for (int r = 0; r < 2; ++r) {
        fx4 p = acc[r][0] * acc[r][0];
        #pragma unroll
        for (int c = 1; c < 4; ++c) p += acc[r][c] * acc[r][c];
        #pragma unroll
        for (int off = 1; off <= 8; off <<= 1)
            #pragma unroll
            for (int i2 = 0; i2 < 4; ++i2) p[i2] += __shfl_xor(p[i2], off, 64);
        pr[r] = p;
    }

    __syncthreads();
    if (lm == 0) {
        #pragma unroll
        for (int r = 0; r < 2; ++r)
            #pragma unroll
            for (int i = 0; i < 4; ++i)
                norm2[(wr0 + r * 16 + q * 4 + i) * 2 + (w & 1)] = pr[r][i];
    }
    __syncthreads();
    if (t < 64) {
        float s = norm2[t * 2] + norm2[t * 2 + 1];
        invn[t] = 1.0f / fmaxf(sqrtf(s), 1e-12f);
    }
    __syncthreads();

    float cS[4] = {}, cQ[4] = {};
    #pragma unroll
    for (int r = 0; r < 2; ++r) {
        int rowb = wr0 + r * 16 + q * 4;
        fx4 iv = *(const fx4*)&invn[rowb];
        #pragma unroll
        for (int c = 0; c < 4; ++c) {
            fx4 v = acc[r][c] * iv;
            int col = wc0 + c * 16 + lm;
            #pragma unroll
            for (int i = 0; i < 4; ++i) {
                int gr = r0 + rowb + i;
                if (gr < n) {
                    s1b[(size_t)gr * 128 + col] = f2bf(v[i]);
                    cS[c] += v[i];
                    cQ[c] += v[i] * v[i];
                }
            }
        }
    }
    #pragma unroll
    for (int off = 16; off <= 32; off <<= 1)
        #pragma unroll
        for (int c = 0; c < 4; ++c) {
            cS[c] += __shfl_xor(cS[c], off, 64);
            cQ[c] += __shfl_xor(cQ[c], off, 64);
        }
    if (q == 0) {
        #pragma unroll
        for (int c = 0; c < 4; ++c) {
            int col = wc0 + c * 16 + lm;
            statS[col * 2 + (w >> 1)] = cS[c];
            statQ[col * 2 + (w >> 1)] = cQ[c];
        }
    }
    __syncthreads();
    if (t < 128) {
        float* sp = stats + ((int)blockIdx.x & 7) * 256;   // 8-way split
        atomicAdd(&sp[t],       statS[t * 2] + statS[t * 2 + 1]);
        atomicAdd(&sp[128 + t], statQ[t * 2] + statQ[t * 2 + 1]);
    }
}

// ---- GEMM2 (bf16 MFMA) with inline BN finalize. Block 64x128, BK=32,
// 4 rounds, grid 1563. BN coeffs from the 8 split stats copies.
__global__ __launch_bounds__(256, 4) void k_gemm2(
        const unsigned short* __restrict__ s1b, const unsigned short* __restrict__ wB2p,
        const float* __restrict__ stats, const float* __restrict__ gamma,
        const float* __restrict__ beta, const float* __restrict__ b2l,
        unsigned short* __restrict__ y2b, float* __restrict__ rbuf, int n) {
    __shared__ __align__(16) unsigned short xs[64 * 32];    // 4KB
    __shared__ __align__(16) unsigned short ws[128 * 32];   // 8KB
    __shared__ __align__(16) float abuf[128];
    __shared__ __align__(16) float bbuf[128];
    int t = threadIdx.x;
    int w = t >> 6, L = t & 63;
    int q = L >> 4, lm = L & 15;
    int wr0 = (w >> 1) * 32, wc0 = (w & 1) * 64;
    int r0 = blockIdx.x * 64;

    if (t < 128) {
        float s = 0.f, qv = 0.f;
        #pragma unroll
        for (int k = 0; k < 8; ++k) {
            s  += stats[k * 256 + t];
            qv += stats[k * 256 + 128 + t];
        }
        float fn = (float)n;
        float mean = s / fn;
        float var = qv / fn - mean * mean;   // biased variance
        float istd = rsqrtf(var + 1e-5f);
        float a = gamma[t] * istd;
        abuf[t] = a;
        bbuf[t] = beta[t] - mean * a;
    }
    __syncthreads();   // abuf/bbuf visible to all

    fx4 acc[2][4];
    fx4 z4 = {0.f, 0.f, 0.f, 0.f};
    #pragma unroll
    for (int r = 0; r < 2; ++r)
        #pragma unroll
        for (int c = 0; c < 4; ++c) acc[r][c] = z4;

    for (int kt = 0; kt < 4; ++kt) {
        int kbase = kt * 32;
        __syncthreads();
        {
            int row = t >> 2, p = t & 3;
            int sl = p ^ ((row >> 1) & 3);
            int gr = r0 + row; gr = gr < n ? gr : (n - 1);
            GLL16(s1b + (size_t)gr * 128 + kbase + sl * 8, &xs[t * 8]);
            #pragma unroll
            for (int it = 0; it < 2; ++it) {
                int i = t + it * 256;
                int wrow = i >> 2, wp = i & 3;
                int wsl = wp ^ ((wrow >> 1) & 3);
                GLL16(wB2p + (size_t)wrow * 128 + kbase + wsl * 8, &ws[i * 8]);
            }
        }
        __syncthreads();   // DMA drained -> tiles visible
        int kb = kbase + q * 8;
        fx4 a0 = *(const fx4*)&abuf[kb];
        fx4 a1 = *(const fx4*)&abuf[kb + 4];
        fx4 b0 = *(const fx4*)&bbuf[kb];
        fx4 b1 = *(const fx4*)&bbuf[kb + 4];
        s8v af[2], bfr[4];
        #pragma unroll
        for (int r = 0; r < 2; ++r) {
            int row = wr0 + r * 16 + lm;
            s8v sv = *(const s8v*)&xs[row * 32 + ((q ^ ((row >> 1) & 3)) << 3)];
            union { s8v v; unsigned short u[8]; } o;
            #pragma unroll
            for (int u = 0; u < 4; ++u) {
                float h0 = fmaxf(fmaf(a0[u], bf2f((unsigned short)sv[u]), b0[u]), 0.f);
                float h1 = fmaxf(fmaf(a1[u], bf2f((unsigned short)sv[u + 4]), b1[u]), 0.f);
                o.u[u]     = f2bf(h0);
                o.u[u + 4] = f2bf(h1);
            }
            af[r] = o.v;
        }
        #pragma unroll
        for (int c = 0; c < 4; ++c) {
            int row = wc0 + c * 16 + lm;
            bfr[c] = *(const s8v*)&ws[row * 32 + ((q ^ ((row >> 1) & 3)) << 3)];
        }
        #pragma unroll
        for (int r = 0; r < 2; ++r)
            #pragma unroll
            for (int c = 0; c < 4; ++c)
                acc[r][c] = __builtin_amdgcn_mfma_f32_16x16x32_bf16(af[r], bfr[c], acc[r][c], 0, 0, 0);
    }

    // epilogue: y2b bf16 stride 64 (j<47) / rbuf fp32 stride 48 + b2l (j 47..93)
    #pragma unroll
    for (int c = 0; c < 4; ++c) {
        int col = wc0 + c * 16 + lm;
        float bb = (col >= 47 && col < 94) ? b2l[col - 47] : 0.f;
        #pragma unroll
        for (int r = 0; r < 2; ++r) {
            int rowb = wr0 + r * 16 + q * 4;
            #pragma unroll
            for (int i = 0; i < 4; ++i) {
                int gr = r0 + rowb + i;
                if (gr >= n) continue;
                float v = acc[r][c][i];
                if (col < 47)      y2b[(size_t)gr * 64 + col] = f2bf(v);
                else if (col < 94) rbuf[(size_t)gr * 48 + (col - 47)] = v + bb;
            }
        }
    }
}

// ---- layer-2 gather + combine + L2-norm. 16 lanes/node (lane owns 4 ch),
// 16 nodes/block, 8-edge unroll -> 4 independent load chains per wave.
__global__ __launch_bounds__(256) void k_gather2_final(
        const unsigned short* __restrict__ y2b, const float* __restrict__ rbuf,
        const int* __restrict__ rowStart, const int* __restrict__ deg,
        const int* __restrict__ srcIdx, float* __restrict__ out, int n) {
    int t = threadIdx.x;
    int q = t & 15, grp = t >> 4;
    int node = blockIdx.x * 16 + grp;
    if (node >= n) return;
    int beg = rowStart[node];
    int d = deg[node];
    int end = beg + d;
    float acc[4] = {0.f, 0.f, 0.f, 0.f};
    int e = beg;
    for (; e + 8 <= end; e += 8) {
        int s0 = srcIdx[e],     s1v = srcIdx[e + 1];
        int s2 = srcIdx[e + 2], s3  = srcIdx[e + 3];
        int s4 = srcIdx[e + 4], s5  = srcIdx[e + 5];
        int s6 = srcIdx[e + 6], s7  = srcIdx[e + 7];
        s4v v0 = *(const s4v*)(y2b + (size_t)s0 * 64 + q * 4);
        s4v v1 = *(const s4v*)(y2b + (size_t)s1v * 64 + q * 4);
        s4v v2 = *(const s4v*)(y2b + (size_t)s2 * 64 + q * 4);
        s4v v3 = *(const s4v*)(y2b + (size_t)s3 * 64 + q * 4);
        s4v v4 = *(const s4v*)(y2b + (size_t)s4 * 64 + q * 4);
        s4v v5 = *(const s4v*)(y2b + (size_t)s5 * 64 + q * 4);
        s4v v6 = *(const s4v*)(y2b + (size_t)s6 * 64 + q * 4);
        s4v v7 = *(const s4v*)(y2b + (size_t)s7 * 64 + q * 4);
        #pragma unroll
        for (int u = 0; u < 4; ++u) {
            acc[u] += (bf2f((unsigned short)v0[u]) + bf2f((unsigned short)v1[u]))
                    + (bf2f((unsigned short)v2[u]) + bf2f((unsigned short)v3[u]))
                    + (bf2f((unsigned short)v4[u]) + bf2f((unsigned short)v5[u]))
                    + (bf2f((unsigned short)v6[u]) + bf2f((unsigned short)v7[u]));
        }
    }
    for (; e + 4 <= end; e += 4) {
        int s0 = srcIdx[e],     s1v = srcIdx[e + 1];
        int s2 = srcIdx[e + 2], s3  = srcIdx[e + 3];
        s4v v0 = *(const s4v*)(y2b + (size_t)s0 * 64 + q * 4);
        s4v v1 = *(const s4v*)(y2b + (size_t)s1v * 64 + q * 4);
        s4v v2 = *(const s4v*)(y2b + (size_t)s2 * 64 + q * 4);
        s4v v3 = *(const s4v*)(y2b + (size_t)s3 * 64 + q * 4);
        #pragma unroll
        for (int u = 0; u < 4; ++u)
            acc[u] += (bf2f((unsigned short)v0[u]) + bf2f((unsigned short)v1[u]))
                    + (bf2f((unsigned short)v2[u]) + bf2f((unsigned short)v3[u]));
    }
    for (; e < end; ++e) {
        s4v v0 = *(const s4v*)(y2b + (size_t)srcIdx[e] * 64 + q * 4);
        #pragma unroll
        for (int u = 0; u < 4; ++u) acc[u] += bf2f((unsigned short)v0[u]);
    }
    float ic = 1.0f / fmaxf((float)d, 1.0f);
    fx4 rb = *(const fx4*)(rbuf + (size_t)node * 48 + q * 4);
    float vi[4];
    float ss = 0.f;
    #pragma unroll
    for (int u = 0; u < 4; ++u) {
        int ch = q * 4 + u;
        float v = (ch < 47) ? (acc[u] * ic + rb[u]) : 0.f;   // select masks pad (NaN-safe)
        vi[u] = v;
        ss += v * v;
    }
    #pragma unroll
    for (int off = 1; off <= 8; off <<= 1) ss += __shfl_xor(ss, off, 64);
    float inv = 1.0f / fmaxf(sqrtf(ss), 1e-12f);
    #pragma unroll
    for (int u = 0; u < 4; ++u) {
        int ch = q * 4 + u;
        if (ch < 47) out[(size_t)node * 47 + ch] = vi[u] * inv;
    }
}

extern "C" void kernel_launch(void* const* d_in, const int* in_sizes, int n_in,
                              void* d_out, int out_size, void* d_ws, size_t ws_size,
                              hipStream_t stream) {
    const float* x     = (const float*)d_in[0];
    const int*   ei    = (const int*)d_in[1];
    const float* w1l   = (const float*)d_in[2];
    const float* b1l   = (const float*)d_in[3];
    const float* w1r   = (const float*)d_in[4];
    const float* gamma = (const float*)d_in[5];
    const float* beta  = (const float*)d_in[6];
    const float* w2l   = (const float*)d_in[7];
    const float* b2l   = (const float*)d_in[8];
    const float* w2r   = (const float*)d_in[9];
    float* out = (float*)d_out;

    int n  = in_sizes[0] / 128;   // 100000
    int nE = in_sizes[1] / 2;     // 800000

    int NB  = (n + 255) >> 8;                    // 391 buckets
    int nCh = (nE + CSR_CHUNK - 1) / CSR_CHUNK;  // 98 chunks

    // ---- workspace layout ----
    // deg[n](int) | stats[2048](f32, 8 copies) | rowStart[n] | meta[n]
    // | srcIdx[nE] | xb[128n bf16] | aggb[128n bf16] | s1b[128n bf16]
    // | wB1 | wB2p
    // meta: counts[nCh*512] then bucketStart at +60000, gcur[512] at +61000.
    // pairs[nE] overlays s1b (dead until gemm1).
    // y2b[64n bf16, 1 line/row] + rbuf[48n f32] overlay xb+aggb.
    int* deg       = (int*)d_ws;
    float* stats   = (float*)(deg + n);
    int* rowStart  = (int*)(stats + 2048);
    int* meta      = rowStart + n;
    int* srcIdx    = meta + n;
    unsigned short* xb   = (unsigned short*)(srcIdx + nE);
    unsigned short* aggb = xb + (size_t)n * 128;
    unsigned short* s1b  = aggb + (size_t)n * 128;
    unsigned short* wB1  = s1b + (size_t)n * 128;
    unsigned short* wB2p = wB1 + 32768;
    int* counts      = meta;
    int* bucketStart = meta + 60000;
    int* gcur        = meta + 61000;
    int* pairs       = (int*)s1b;             // packed (src<<8)|(dst&255)
    unsigned short* y2b = xb;                 // stride 64 shorts (128B/row)
    float* rbuf = (float*)(y2b + (size_t)n * 64);   // stride 48 f32

    int prepTotal  = n * 16 + 32768 + 16384 + 2048;
    int prepBlocks = (prepTotal + 255) / 256;

    // 1: prep (xcast | weight casts | stats zero | bcount histograms)
    k_prep<<<prepBlocks + nCh, 256, 0, stream>>>(
        x, w1l, w1r, w2l, w2r, ei, xb, wB1, wB2p, stats, counts, n, nE, prepBlocks);
    // 2-4: CSR build (bucketed counting sort, runtime range reservation)
    k_bmeta<<<1, 256, 0, stream>>>(counts, bucketStart, gcur, nCh, NB);
    k_bfill<<<nCh, 256, 0, stream>>>(ei, counts, gcur, pairs, nE);
    k_csr<<<NB, 256, 0, stream>>>(pairs, bucketStart, deg, rowStart, srcIdx, n);
    // 5-6: layer 1
    k_gather1<<<(n + 15) / 16, 256, 0, stream>>>(xb, rowStart, deg, srcIdx, aggb, n);
    k_gemm1<<<(n + 63) / 64, 256, 0, stream>>>(xb, aggb, wB1, b1l, s1b, stats, n);
    // 7-8: layer 2 (BN finalize inlined in gemm2)
    k_gemm2<<<(n + 63) / 64, 256, 0, stream>>>(
        s1b, wB2p, stats, gamma, beta, b2l, y2b, rbuf, n);
    k_gather2_final<<<(n + 15) / 16, 256, 0, stream>>>(y2b, rbuf, rowStart, deg, srcIdx, out, n);
}